// Round 6
// baseline (848.408 us; speedup 1.0000x reference)
//
#include <hip/hip_runtime.h>
#include <stdint.h>

// ---------------------------------------------------------------------------
// DynamicTransformerBlock. I/O = FP32 (per reference dtypes); MFMA math in
// bf16 with fp32 accum; norms in fp32. 3x3 convs (except tiny CI=3 seg conv)
// are implicit-GEMM MFMA: K = 9*CI, A = shifted pixel-major bf16 input,
// B^T = prepacked bf16 weights [o][tap][ci].
// B=2, CV=256, CPOS=64, CQK=320, DP=64, H=W=64, N=4096, IC=3, NH=128
// Outputs (concat, fp32): res (2,256,64,64) | out2 (2,256,64,64) | cor (2,4096,4096)
// All outputs written bf16-rounded. Workspace ~62 MB. d_out overlays: cor
// region hosts query/key bf16 concat until the cor GEMM runs; res region
// hosts pre-pono `out` until the final conv.
// gemm_pv5: both softmax-V GEMMs (mode via blockIdx.y), tile 32x256.
// B fragments loaded DIRECT from global (V is L2-resident; no B LDS, no
// bank conflicts); A (exp'd cor) in ping-pong LDS -> ONE barrier per K-step;
// 2-deep register prefetch so loads have ~2 full steps of latency cover.
// ---------------------------------------------------------------------------

#define DEV static __device__ __forceinline__

typedef short short8 __attribute__((ext_vector_type(8)));
typedef float floatx4 __attribute__((ext_vector_type(4)));

DEV float bf2f(unsigned short b) { return __uint_as_float(((unsigned int)b) << 16); }
DEV unsigned short f2bf(float f) {
  unsigned int u = __float_as_uint(f);
  u += 0x7FFFu + ((u >> 16) & 1u);   // RNE
  return (unsigned short)(u >> 16);
}
DEV float bfround(float f) { return bf2f(f2bf(f)); }

// ---------------------------------------------------------------------------
// flat fp32 -> bf16 convert
// ---------------------------------------------------------------------------
__global__ __launch_bounds__(256)
void cvt_f2b(const float* __restrict__ in, unsigned short* __restrict__ out, int n)
{
  int i = blockIdx.x * 256 + threadIdx.x;
  if (i < n) out[i] = f2bf(in[i]);
}

// ---------------------------------------------------------------------------
// conv weight prepack: fp32 (CO, CI, 3, 3) -> bf16 [o][tap][ci] (K-contig)
// ---------------------------------------------------------------------------
__global__ __launch_bounds__(256)
void prep_w9(const float* __restrict__ w, unsigned short* __restrict__ w9,
             int CO, int CI)
{
  int i = blockIdx.x * 256 + threadIdx.x;
  int tot = CO * CI * 9;
  if (i >= tot) return;
  int s = i % 9, rest = i / 9;
  int ci = rest % CI, o = rest / CI;
  w9[(long long)o * 9 * CI + s * CI + ci] = f2bf(w[i]);
}

// ---------------------------------------------------------------------------
// column sumsq -> 1/(||col||+eps). x (b,256,4096). grid (128, B), block 256.
// ---------------------------------------------------------------------------
__global__ __launch_bounds__(256)
void colnorm(const float* __restrict__ x, float* __restrict__ rnorm)
{
  int b = blockIdx.y, t = threadIdx.x;
  int n = (blockIdx.x << 5) + (t & 31);
  int cg = t >> 5;
  const float* base = x + ((long long)b << 20) + n;
  float s = 0.f;
#pragma unroll
  for (int c8 = 0; c8 < 32; c8++) {
    float v = base[((long long)(cg * 32 + c8)) << 12];
    s += v * v;
  }
  __shared__ float red[256];
  red[t] = s; __syncthreads();
  for (int st = 128; st >= 32; st >>= 1) {
    if (t < st) red[t] += red[t + st];
    __syncthreads();
  }
  if (t < 32)
    rnorm[(b << 12) + n] = 1.f / (sqrtf(red[t]) + 2.2204460492503131e-16f);
}

// ---------------------------------------------------------------------------
// build query/key via LDS transpose: qt (b, n, 320) bf16 =
//   [ x[c][n] * rnorm[n] (c<256) , pos[c][n] (64) ]
// grid (64, 5, B): by<4 -> x channel-tile by*64, by==4 -> pos tile. block 256.
// ---------------------------------------------------------------------------
__global__ __launch_bounds__(256)
void build_qk3(const float* __restrict__ x, const float* __restrict__ pos,
               const float* __restrict__ rnorm, unsigned short* __restrict__ qt)
{
  __shared__ float tile[64][65];
  int b = blockIdx.z, by = blockIdx.y;
  int n0 = blockIdx.x << 6;
  int tx = threadIdx.x & 63, tg = threadIdx.x >> 6;
  const float* ib;
  int c0;
  if (by < 4) { ib = x + ((long long)b << 20) + ((long long)(by << 6) << 12); c0 = by << 6; }
  else        { ib = pos; c0 = 256; }
#pragma unroll
  for (int i = 0; i < 16; i++) {
    int r = tg * 16 + i;
    tile[r][tx] = ib[((long long)r << 12) + n0 + tx];
  }
  __syncthreads();
#pragma unroll
  for (int i = 0; i < 16; i++) {
    int r = tg * 16 + i;   // column n0+r
    float sc = (by < 4) ? rnorm[(b << 12) + n0 + r] : 1.f;
    qt[((long long)(b * 4096 + n0 + r)) * 320 + c0 + tx] = f2bf(tile[tx][r] * sc);
  }
}

// ---------------------------------------------------------------------------
// fp32 (b,C,4096) -> bf16 (b,4096,C) transpose. grid (64, C/64, B), block 256
// ---------------------------------------------------------------------------
__global__ __launch_bounds__(256)
void transpose_c(const float* __restrict__ in, unsigned short* __restrict__ out, int C)
{
  __shared__ float tile[64][65];
  int b = blockIdx.z;
  int c0 = blockIdx.y << 6;
  int n0 = blockIdx.x << 6;
  const float* ib = in + (long long)b * C * 4096;
  unsigned short* ob = out + (long long)b * C * 4096;
  int tx = threadIdx.x & 63, tg = threadIdx.x >> 6;
#pragma unroll
  for (int i = 0; i < 16; i++) {
    int r = tg * 16 + i;
    tile[r][tx] = ib[((long long)(c0 + r) << 12) + n0 + tx];
  }
  __syncthreads();
#pragma unroll
  for (int i = 0; i < 16; i++) {
    int r = tg * 16 + i;
    ob[(long long)(n0 + r) * C + c0 + tx] = f2bf(tile[tx][r]);
  }
}

// ---------------------------------------------------------------------------
// MFMA GEMM:  C[M,N] = alpha * A(M,K) * Bt(N,K)^T (+bias). A,Bt bf16
// K-contiguous. M%128==0, K%32==0, N guarded. Outputs: Cb bf16; Cf fp32
// (bf16-rounded, used for cor); Cm bit-packed sign mask (ballot).
// block 256 = 4 waves (2x2), wave tile 64x64 via 4x4 of 16x16x32 MFMA.
// ---------------------------------------------------------------------------
__global__ __launch_bounds__(256)
void gemm_bt(const unsigned short* __restrict__ A, long long sAb, int lda,
             const unsigned short* __restrict__ Bt, long long sBb, int ldb,
             int Ncols, int K, float alpha,
             const float* __restrict__ bias, int biasMode,
             unsigned short* __restrict__ Cb, long long sCbb, int ldcb,
             float* __restrict__ Cf, long long sCfb, int ldcf,
             unsigned short* __restrict__ Cm)
{
  __shared__ unsigned short As[128][40];
  __shared__ unsigned short Bs[128][40];
  int bz = blockIdx.z;
  const unsigned short* Ab = A + bz * sAb;
  const unsigned short* Bb = Bt + bz * sBb;
  int m0 = blockIdx.y << 7, n0 = blockIdx.x << 7;
  int t = threadIdx.x;
  int lane = t & 63, wave = t >> 6, quad = lane >> 4, l16 = lane & 15;
  int wm = (wave >> 1) << 6, wn = (wave & 1) << 6;

  floatx4 acc[4][4] = {};

  for (int k0 = 0; k0 < K; k0 += 32) {
#pragma unroll
    for (int s = 0; s < 2; s++) {
      int idx = t + (s << 8);
      int row = idx >> 2, ch = (idx & 3) << 3;
      short8 av = *(const short8*)(Ab + (long long)(m0 + row) * lda + k0 + ch);
      *(short8*)&As[row][ch] = av;
      short8 bv = {};
      if (n0 + row < Ncols) bv = *(const short8*)(Bb + (long long)(n0 + row) * ldb + k0 + ch);
      *(short8*)&Bs[row][ch] = bv;
    }
    __syncthreads();
    short8 af[4], bfv[4];
#pragma unroll
    for (int i = 0; i < 4; i++) af[i] = *(const short8*)&As[wm + (i << 4) + l16][quad << 3];
#pragma unroll
    for (int j = 0; j < 4; j++) bfv[j] = *(const short8*)&Bs[wn + (j << 4) + l16][quad << 3];
#pragma unroll
    for (int i = 0; i < 4; i++)
#pragma unroll
      for (int j = 0; j < 4; j++)
        acc[i][j] = __builtin_amdgcn_mfma_f32_16x16x32_bf16(af[i], bfv[j], acc[i][j], 0, 0, 0);
    __syncthreads();
  }

#pragma unroll
  for (int j = 0; j < 4; j++) {
    int col = n0 + wn + (j << 4) + l16;
    if (col >= Ncols) continue;
    float bcol = (biasMode == 1) ? bias[col] : 0.f;
#pragma unroll
    for (int i = 0; i < 4; i++) {
#pragma unroll
      for (int r = 0; r < 4; r++) {
        int row = m0 + wm + (i << 4) + (quad << 2) + r;
        float vv = acc[i][j][r] * alpha + bcol;
        if (biasMode == 2) vv += bias[row];
        if (Cb) Cb[bz * sCbb + (long long)row * ldcb + col] = f2bf(vv);
        if (Cf) Cf[bz * sCfb + (long long)row * ldcf + col] = bfround(vv);
        if (Cm) {  // only used with Ncols=4096 (no divergent continue above)
          unsigned long long bal = __ballot(vv > 0.f);
          if (l16 == 0)
            Cm[(long long)bz * 4096 * 256 + (long long)row * 256 + ((n0 + wn + (j << 4)) >> 4)]
              = (unsigned short)(bal >> (quad << 4));
        }
      }
    }
  }
}

// ---------------------------------------------------------------------------
// Implicit-GEMM 3x3 SAME conv, MFMA bf16.
//   C[pixel, o] = sum_{tap, ci} Xt[shift_tap(pixel), ci] * W9[o][tap][ci] + b[o]
// Xt: (bz, 4096, CI) bf16 pixel-major; W9: (CO, 9*CI) bf16.
// Outputs: Cb bf16 (n, CO) [opt relu]  and/or  Cf fp32 (CO, n) [opt +addT,
// opt bf16-round]. grid (CO/128, 32, B), block 256. 64x64 image, SAME pad.
// ---------------------------------------------------------------------------
__global__ __launch_bounds__(256)
void gemm_conv(const unsigned short* __restrict__ Xt, int CI,
               const unsigned short* __restrict__ W9, int CO,
               const float* __restrict__ bias,
               unsigned short* __restrict__ Cb, int relu,
               float* __restrict__ Cf, const float* __restrict__ addT, int rnd)
{
  __shared__ unsigned short As[128][40];
  __shared__ unsigned short Bs[128][40];
  int bz = blockIdx.z;
  const unsigned short* Xb = Xt + (long long)bz * 4096 * CI;
  int m0 = blockIdx.y << 7, n0 = blockIdx.x << 7;
  int t = threadIdx.x;
  int lane = t & 63, wave = t >> 6, quad = lane >> 4, l16 = lane & 15;
  int wm = (wave >> 1) << 6, wn = (wave & 1) << 6;
  int K9 = 9 * CI;

  floatx4 acc[4][4] = {};

  for (int tap = 0; tap < 9; ++tap) {
    int dy = tap / 3 - 1, dx = tap % 3 - 1;
    int off = dy * 64 + dx;
    for (int kc = 0; kc < CI; kc += 32) {
#pragma unroll
      for (int s = 0; s < 2; s++) {
        int idx = t + (s << 8);
        int row = idx >> 2, ch = (idx & 3) << 3;
        int p = m0 + row;                       // pixel in [0,4096)
        int y = (p >> 6) + dy, x = (p & 63) + dx;
        short8 av = {};
        if ((unsigned)y < 64u && (unsigned)x < 64u)
          av = *(const short8*)(Xb + (long long)(p + off) * CI + kc + ch);
        *(short8*)&As[row][ch] = av;
        // CO is a multiple of 128 here -> no N guard
        short8 bv = *(const short8*)(W9 + (long long)(n0 + row) * K9 + tap * CI + kc + ch);
        *(short8*)&Bs[row][ch] = bv;
      }
      __syncthreads();
      short8 af[4], bfv[4];
#pragma unroll
      for (int i = 0; i < 4; i++) af[i] = *(const short8*)&As[wm + (i << 4) + l16][quad << 3];
#pragma unroll
      for (int j = 0; j < 4; j++) bfv[j] = *(const short8*)&Bs[wn + (j << 4) + l16][quad << 3];
#pragma unroll
      for (int i = 0; i < 4; i++)
#pragma unroll
        for (int j = 0; j < 4; j++)
          acc[i][j] = __builtin_amdgcn_mfma_f32_16x16x32_bf16(af[i], bfv[j], acc[i][j], 0, 0, 0);
      __syncthreads();
    }
  }

#pragma unroll
  for (int j = 0; j < 4; j++) {
    int col = n0 + wn + (j << 4) + l16;        // output channel
    float bcol = bias[col];
#pragma unroll
    for (int i = 0; i < 4; i++) {
#pragma unroll
      for (int r = 0; r < 4; r++) {
        int row = m0 + wm + (i << 4) + (quad << 2) + r;   // pixel
        float vv = acc[i][j][r] + bcol;
        if (relu) vv = fmaxf(vv, 0.f);
        if (Cb) Cb[((long long)bz * 4096 + row) * CO + col] = f2bf(vv);
        if (Cf) {
          long long oi = ((long long)bz * CO + col) * 4096 + row;
          float ov = vv;
          if (addT) ov += addT[oi];
          Cf[oi] = rnd ? bfround(ov) : ov;
        }
      }
    }
  }
}

// ---------------------------------------------------------------------------
// Per-row softmax stats over fp32 cor (4096/row). grid 8192, block 256.
// statA[row] = {rmax1, 1/sum1, rmax2, 1/sum2};  confF[row] = conf.
// ---------------------------------------------------------------------------
__global__ __launch_bounds__(256)
void stats_rows(const float* __restrict__ corF,
                const unsigned char* __restrict__ mbits,
                float4* __restrict__ statA, float* __restrict__ confF)
{
  long long row = blockIdx.x;
  const float4* cr = (const float4*)(corF + (row << 12));
  const unsigned char* mr = mbits + row * 512;
  int t = threadIdx.x;

  float lg[16]; unsigned int mk[16];
#pragma unroll
  for (int i = 0; i < 4; i++) {
    float4 cc = cr[i * 256 + t];
    unsigned char mb = mr[(i * 256 + t) >> 1];
    int sh = (t & 1) << 2;
    lg[4 * i + 0] = cc.x; lg[4 * i + 1] = cc.y;
    lg[4 * i + 2] = cc.z; lg[4 * i + 3] = cc.w;
#pragma unroll
    for (int j = 0; j < 4; j++) mk[4 * i + j] = (mb >> (sh + j)) & 1u;
  }
  float m1 = -3.0e38f, m2 = -3.0e38f; int cnt = 0;
#pragma unroll
  for (int e = 0; e < 16; e++) {
    m1 = fmaxf(m1, lg[e]);
    if (!mk[e]) m2 = fmaxf(m2, lg[e]);
    cnt += (int)mk[e];
  }
  __shared__ float4 red4[256];
  red4[t] = make_float4(m1, m2, 0.f, 0.f); __syncthreads();
  for (int s = 128; s > 0; s >>= 1) {
    if (t < s) {
      red4[t].x = fmaxf(red4[t].x, red4[t + s].x);
      red4[t].y = fmaxf(red4[t].y, red4[t + s].y);
    }
    __syncthreads();
  }
  float rmax1 = red4[0].x;
  float rmax2 = fmaxf(red4[0].y, -10000.f);
  __syncthreads();

  float s1 = 0.f, cn = 0.f, s2 = 0.f;
#pragma unroll
  for (int e = 0; e < 16; e++) {
    float ex = __expf(fminf(lg[e] - rmax1, 0.f));
    s1 += ex;
    if (mk[e]) cn += ex;
    else s2 += __expf(fminf(lg[e] - rmax2, 0.f));
  }
  red4[t] = make_float4(s1, cn, s2, (float)cnt); __syncthreads();
  for (int s = 128; s > 0; s >>= 1) {
    if (t < s) {
      red4[t].x += red4[t + s].x; red4[t].y += red4[t + s].y;
      red4[t].z += red4[t + s].z; red4[t].w += red4[t + s].w;
    }
    __syncthreads();
  }
  if (t == 0) {
    float4 r = red4[0];
    float sum2 = r.z + r.w * __expf(fminf(-10000.f - rmax2, 0.f));
    statA[row] = make_float4(rmax1, 1.f / fmaxf(r.x, 1e-30f),
                             rmax2, 1.f / fmaxf(sum2, 1e-30f));
    confF[row] = r.y / fmaxf(r.x, 1e-30f);
  }
}

// ---------------------------------------------------------------------------
// Fused P·V GEMM, both modes in one dispatch (mode = blockIdx.y>>1).
// P reconstructed in-register from fp32 cor + bit mask + per-row stats.
// mode 0: P = mask ? exp(cor-rm1) : 0         (epilogue x 1/sum1) -> Cf0 (n,c)
// mode 1: P = mask ? exp(-1e4-rm2) : exp(cor-rm2)  (x 1/sum2)     -> Cf1 (c,n)
// Tile 32(rows) x 256(ALL cols). Block 256 = 4 n-waves, wave 32x64 = 2x4
// MFMA. Grid (128, 2B) = 512 blocks.
// B fragments DIRECT from global (V L2-resident; no B LDS / bank conflicts).
// A in ping-pong LDS (one barrier per K-step). 2-deep register prefetch:
// loads for step k+2 issue at step k -> ~2 steps of latency cover.
// ---------------------------------------------------------------------------
__global__ __launch_bounds__(256, 2)
void gemm_pv5(const float* __restrict__ corF,
              const unsigned char* __restrict__ mbits,
              const float4* __restrict__ statA,
              const unsigned short* __restrict__ Bt0,
              const unsigned short* __restrict__ Bt1,
              float* __restrict__ Cf0, float* __restrict__ Cf1)
{
  __shared__ unsigned short As[2][32][40];
  __shared__ float2 sstat[32];           // (-rm*log2e, iv) per A row
  int bz = blockIdx.y & 1, mode = blockIdx.y >> 1;
  const float* corb = corF + (long long)bz * 4096 * 4096;
  const unsigned char* mbb = mbits + (long long)bz * 4096 * 512;
  const unsigned short* Bb = (mode ? Bt1 : Bt0) + (long long)bz * 256 * 4096;
  int m0 = blockIdx.x << 5;
  int t = threadIdx.x;
  int lane = t & 63, wave = t >> 6, quad = lane >> 4, l16 = lane & 15;
  int wn = wave << 6;
  const float L2E = 1.44269504088896340736f;

  if (t < 32) {
    float4 s = statA[(long long)bz * 4096 + m0 + t];
    float rm = mode ? s.z : s.x, iv = mode ? s.w : s.y;
    sstat[t] = make_float2(-rm * L2E, iv);
  }
  __syncthreads();

  // A staging: thread t -> row rA (32 rows), 4-float k-chunk at cA
  int rA = t >> 3, cA = (t & 7) << 2;
  float nrmL = sstat[rA].x;                      // -rm*log2e
  float mvr = exp2f(-10000.f * L2E + nrmL);      // mode1 masked value

  floatx4 acc[2][4] = {};

  const float* cpb = corb + (long long)(m0 + rA) * 4096 + cA;
  const unsigned char* mbp = mbb + (long long)(m0 + rA) * 512;
  // B fragment base: this lane's V row (= output channel wn+l16), k-chunk quad*8
  const unsigned short* pbb = Bb + (long long)(wn + l16) * 4096 + (quad << 3);

  float4 paA, paB; unsigned int mkA, mkB;
  short8 pbA[4], pbB[4];

  auto issueA = [&](int kk, float4& pa, unsigned int& pmk) {
    pa = *(const float4*)(cpb + kk);
    pmk = (unsigned int)(mbp[(kk + cA) >> 3] >> (cA & 7)) & 0xFu;
  };
  auto issueB = [&](int kk, short8* pb) {
#pragma unroll
    for (int j = 0; j < 4; j++)
      pb[j] = *(const short8*)(pbb + (long long)(j << 4) * 4096 + kk);
  };
  auto commit = [&](int p, float4 pa, unsigned int pmk) {
    float cs[4] = {pa.x, pa.y, pa.z, pa.w};
    float vs[4];
#pragma unroll
    for (int j = 0; j < 4; j++) {
      float e = exp2f(fmaf(cs[j], L2E, nrmL));   // exp(c - rm)
      bool mk = (pmk >> j) & 1u;
      vs[j] = mode ? (mk ? mvr : e) : (mk ? e : 0.f);
    }
    unsigned int u01, u23;
    asm("v_cvt_pk_bf16_f32 %0, %1, %2" : "=v"(u01) : "v"(vs[0]), "v"(vs[1]));
    asm("v_cvt_pk_bf16_f32 %0, %1, %2" : "=v"(u23) : "v"(vs[2]), "v"(vs[3]));
    *(unsigned int*)&As[p][rA][cA] = u01;
    *(unsigned int*)&As[p][rA][cA + 2] = u23;
  };
  auto mma = [&](int p, const short8* pb) {
    short8 af[2];
#pragma unroll
    for (int i = 0; i < 2; i++) af[i] = *(const short8*)&As[p][(i << 4) + l16][quad << 3];
#pragma unroll
    for (int i = 0; i < 2; i++)
#pragma unroll
      for (int j = 0; j < 4; j++)
        acc[i][j] = __builtin_amdgcn_mfma_f32_16x16x32_bf16(af[i], pb[j], acc[i][j], 0, 0, 0);
  };

  // prologue: prefetch steps 0 and 1
  issueA(0, paA, mkA); issueB(0, pbA);
  issueA(32, paB, mkB); issueB(32, pbB);

  for (int k0 = 0; k0 < 4096; k0 += 64) {
    // even step (buffer 0)
    commit(0, paA, mkA);
    if (k0 + 64 < 4096) issueA(k0 + 64, paA, mkA);
    __syncthreads();
    mma(0, pbA);
    if (k0 + 64 < 4096) issueB(k0 + 64, pbA);
    // odd step (buffer 1)
    commit(1, paB, mkB);
    if (k0 + 96 < 4096) issueA(k0 + 96, paB, mkB);
    __syncthreads();
    mma(1, pbB);
    if (k0 + 96 < 4096) issueB(k0 + 96, pbB);
  }

#pragma unroll
  for (int j = 0; j < 4; j++) {
    int col = wn + (j << 4) + l16;        // c index < 256
#pragma unroll
    for (int i = 0; i < 2; i++) {
#pragma unroll
      for (int r = 0; r < 4; r++) {
        int lrow = (i << 4) + (quad << 2) + r;
        int row = m0 + lrow;
        float vv = bfround(acc[i][j][r] * sstat[lrow].y);   // x 1/sum
        if (mode) Cf1[(long long)bz * 256 * 4096 + (long long)col * 4096 + row] = vv;
        else      Cf0[(long long)bz * 4096 * 256 + (long long)row * 256 + col] = vv;
      }
    }
  }
}

// ---------------------------------------------------------------------------
// instance-norm stats of q (fp32) over spatial. grid (256, 2), block 256.
// ---------------------------------------------------------------------------
__global__ __launch_bounds__(256)
void inorm_stats(const float* __restrict__ q, float* __restrict__ mu, float* __restrict__ rs)
{
  int c = blockIdx.x, b = blockIdx.y, t = threadIdx.x;
  const float* base = q + ((long long)(b * 256 + c) << 12);
  float s = 0.f, s2 = 0.f;
  for (int i = t; i < 4096; i += 256) { float v = base[i]; s += v; s2 += v * v; }
  __shared__ float r1[256], r2[256];
  r1[t] = s; r2[t] = s2; __syncthreads();
  for (int st = 128; st > 0; st >>= 1) {
    if (t < st) { r1[t] += r1[t + st]; r2[t] += r2[t + st]; }
    __syncthreads();
  }
  if (t == 0) {
    float m = r1[0] * (1.f / 4096.f);
    float var = fmaxf(r2[0] * (1.f / 4096.f) - m * m, 0.f);
    mu[b * 256 + c] = m;
    rs[b * 256 + c] = rsqrtf(var + 1e-5f);
  }
}

// ---------------------------------------------------------------------------
// direct 3x3 SAME conv, fp32 in/out, weights (fp32) in LDS.
// grid (16, CO, B), block 256 (4 rows). Only used for the tiny CI=3 seg conv.
// ---------------------------------------------------------------------------
__global__ __launch_bounds__(256)
void conv3x3(const float* __restrict__ inF,
             const float* __restrict__ wgt, const float* __restrict__ bias,
             int CI, int CO, const float* __restrict__ addF,
             float* __restrict__ outF, int relu, int rnd)
{
  __shared__ float wsm[2304];
  int b = blockIdx.z, o = blockIdx.y, t = threadIdx.x;
  for (int i = t; i < CI * 9; i += 256) wsm[i] = wgt[(long long)o * CI * 9 + i];
  __syncthreads();
  int x = t & 63, y = (blockIdx.x << 2) + (t >> 6);
  bool ym = y > 0, yp = y < 63, xm = x > 0, xp = x < 63;
  int p = y * 64 + x;
  long long ibase = ((long long)b * CI) << 12;
  float acc = bias[o];
  for (int ci = 0; ci < CI; ci++) {
    const float* wp = &wsm[ci * 9];
    long long ib = ibase + ((long long)ci << 12) + p;
    float v00 = (ym && xm) ? inF[ib - 65] : 0.f;
    float v01 = ym ? inF[ib - 64] : 0.f;
    float v02 = (ym && xp) ? inF[ib - 63] : 0.f;
    float v10 = xm ? inF[ib - 1] : 0.f;
    float v11 = inF[ib];
    float v12 = xp ? inF[ib + 1] : 0.f;
    float v20 = (yp && xm) ? inF[ib + 63] : 0.f;
    float v21 = yp ? inF[ib + 64] : 0.f;
    float v22 = (yp && xp) ? inF[ib + 65] : 0.f;
    acc += v00 * wp[0] + v01 * wp[1] + v02 * wp[2]
         + v10 * wp[3] + v11 * wp[4] + v12 * wp[5]
         + v20 * wp[6] + v21 * wp[7] + v22 * wp[8];
  }
  if (relu) acc = fmaxf(acc, 0.f);
  long long oidx = (((long long)(b * CO + o)) << 12) + p;
  if (addF) acc += addF[oidx];
  outF[oidx] = rnd ? bfround(acc) : acc;
}

// ---------------------------------------------------------------------------
// pono epilogue: t = out + (1-conf)*spade + q; y = channel-norm(t). fp32 (c,n).
// Also emits y transposed as bf16 (n,c) for the residual conv GEMMs.
// grid (4096, 2), block 256 (thread = channel)
// ---------------------------------------------------------------------------
__global__ __launch_bounds__(256)
void pono_y(const float* __restrict__ outF, const float* __restrict__ confF,
            const float* __restrict__ gF, const float* __restrict__ bF,
            const float* __restrict__ q, const float* __restrict__ mu,
            const float* __restrict__ rs, float* __restrict__ yF,
            unsigned short* __restrict__ yT)
{
  int n = blockIdx.x, b = blockIdx.y, c = threadIdx.x;
  long long cn = ((long long)(b * 256 + c) << 12) + n;
  float qv = q[cn];
  float sp = (qv - mu[b * 256 + c]) * rs[b * 256 + c] * (1.f + gF[cn]) + bF[cn];
  float cf = confF[b * 4096 + n];
  float tv = outF[((long long)(b * 4096 + n) << 8) + c] + (1.f - cf) * sp + qv;
  __shared__ float red[256];
  red[c] = tv; __syncthreads();
  for (int s = 128; s > 0; s >>= 1) { if (c < s) red[c] += red[c + s]; __syncthreads(); }
  float m = red[0] * (1.f / 256.f); __syncthreads();
  float d = tv - m;
  red[c] = d * d; __syncthreads();
  for (int s = 128; s > 0; s >>= 1) { if (c < s) red[c] += red[c + s]; __syncthreads(); }
  float var = fmaxf(red[0] * (1.f / 256.f), 0.f);
  float yv = d * rsqrtf(var + 1e-5f);
  yF[cn] = yv;
  yT[((long long)(b * 4096 + n) << 8) + c] = f2bf(yv);
}

// ---------------------------------------------------------------------------

extern "C" void kernel_launch(void* const* d_in, const int* in_sizes, int n_in,
                              void* d_out, int out_size, void* d_ws, size_t ws_size,
                              hipStream_t stream)
{
  (void)in_sizes; (void)n_in; (void)out_size; (void)ws_size;
  const int B = 2, CV = 256, CQK = 320, DP = 64, N = 4096, NH = 128, IC = 3;
  const float INV_SQRT_CQK = 0.05590169943749474241f;  // 1/sqrt(320)

  const float* q    = (const float*)d_in[0];
  const float* k    = (const float*)d_in[1];
  const float* v    = (const float*)d_in[2];
  const float* pos  = (const float*)d_in[3];
  const float* seg  = (const float*)d_in[4];
  const float* v2   = (const float*)d_in[5];
  const float* f_w  = (const float*)d_in[6];
  const float* f_b  = (const float*)d_in[7];
  const float* g_w  = (const float*)d_in[8];
  const float* g_b  = (const float*)d_in[9];
  const float* h_w  = (const float*)d_in[10];
  const float* h_b  = (const float*)d_in[11];
  const float* fp_w = (const float*)d_in[12];
  const float* fp_b = (const float*)d_in[13];
  const float* gp_w = (const float*)d_in[14];
  const float* gp_b = (const float*)d_in[15];
  const float* sp_s_w = (const float*)d_in[16];
  const float* sp_s_b = (const float*)d_in[17];
  const float* sp_g_w = (const float*)d_in[18];
  const float* sp_g_b = (const float*)d_in[19];
  const float* sp_b_w = (const float*)d_in[20];
  const float* sp_b_b = (const float*)d_in[21];
  const float* r1_w = (const float*)d_in[22];
  const float* r1_b = (const float*)d_in[23];
  const float* r2_w = (const float*)d_in[24];
  const float* r2_b = (const float*)d_in[25];

  float* res_o  = (float*)d_out;
  float* out2_o = res_o + (long long)B * CV * N;
  float* cor_o  = res_o + 2ll * B * CV * N;

  // d_out overlays (dead until their real producer runs)
  unsigned short* query_t = (unsigned short*)cor_o;
  unsigned short* keyt_t  = query_t + (long long)B * N * CQK;
  float*          outBuf  = res_o;   // exactly B*N*CV floats

  // workspace carve (256B aligned), ~62 MB
  char* wp_ = (char*)d_ws;
  auto take = [&](size_t bytes) -> void* {
    void* r = wp_; wp_ += (bytes + 255) & ~(size_t)255; return r;
  };
  unsigned short* v_t     = (unsigned short*)take((size_t)B * N * CV * 2);
  unsigned short* qf_t    = (unsigned short*)take((size_t)B * N * CQK * 2);
  unsigned short* kf_t    = (unsigned short*)take((size_t)B * N * CQK * 2);
  unsigned short* qp_t    = (unsigned short*)take((size_t)B * N * DP * 2);
  unsigned short* kp_t    = (unsigned short*)take((size_t)B * N * DP * 2);
  unsigned short* vh      = (unsigned short*)take((size_t)B * CV * N * 2);
  unsigned short* v2b     = (unsigned short*)take((size_t)B * CV * N * 2);
  unsigned short* fwB     = (unsigned short*)take((size_t)CQK * CQK * 2);
  unsigned short* gwB     = (unsigned short*)take((size_t)CQK * CQK * 2);
  unsigned short* fpwB    = (unsigned short*)take((size_t)DP * CQK * 2);
  unsigned short* gpwB    = (unsigned short*)take((size_t)DP * CQK * 2);
  unsigned short* hwB     = (unsigned short*)take((size_t)CV * CV * 2);
  unsigned short* maskB16 = (unsigned short*)take((size_t)B * N * 256 * 2);
  float4*         statA   = (float4*)take((size_t)B * N * 16);
  float*          confF   = (float*)take((size_t)B * N * 4);
  float*          muF     = (float*)take((size_t)B * CV * 4);
  float*          rsF     = (float*)take((size_t)B * CV * 4);
  float*          rnormQ  = (float*)take((size_t)B * N * 4);
  float*          rnormK  = (float*)take((size_t)B * N * 4);
  float*          actv    = (float*)take((size_t)B * NH * N * 4);
  float*          gC      = (float*)take((size_t)B * CV * N * 4);
  float*          bC      = (float*)take((size_t)B * CV * N * 4);
  float*          yF      = (float*)take((size_t)B * CV * N * 4);
  // prepacked conv weights, bf16 [o][tap][ci]
  unsigned short* spgW9   = (unsigned short*)take((size_t)CV * 9 * NH * 2);
  unsigned short* spbW9   = (unsigned short*)take((size_t)CV * 9 * NH * 2);
  unsigned short* r1W9    = (unsigned short*)take((size_t)CV * 9 * CV * 2);
  unsigned short* r2W9    = (unsigned short*)take((size_t)CV * 9 * CV * 2);
  // bf16 pixel-major conv activations — reuse regions dead by SPADE time:
  unsigned short* yT      = qf_t;   // B*N*256*2 = 4 MB  <= 5.24 MB (dead after cor GEMM)
  unsigned short* a1T     = kf_t;   // B*N*256*2 = 4 MB  <= 5.24 MB (dead after cor GEMM)
  unsigned short* actvT   = v_t;    // B*N*128*2 = 2 MB  <= 4 MB    (dead after vh GEMM)

  dim3 blk(256);
  auto cvt = [&](const float* in, unsigned short* out, int n) {
    cvt_f2b<<<dim3((n + 255) / 256), blk, 0, stream>>>(in, out, n);
  };
  auto prepw = [&](const float* w, unsigned short* w9, int CO, int CI) {
    prep_w9<<<dim3((CO * CI * 9 + 255) / 256), blk, 0, stream>>>(w, w9, CO, CI);
  };
  auto gemm = [&](const unsigned short* A, long long sAb, int lda,
                  const unsigned short* Bt, long long sBb, int ldb,
                  int M, int Nc, int K, float alpha,
                  const float* bias, int biasMode,
                  unsigned short* Cb, long long sCbb, int ldcb,
                  float* Cf, long long sCfb, int ldcf,
                  unsigned short* Cm) {
    dim3 grid((Nc + 127) / 128, M / 128, B);
    gemm_bt<<<grid, blk, 0, stream>>>(A, sAb, lda, Bt, sBb, ldb, Nc, K, alpha,
                                      bias, biasMode, Cb, sCbb, ldcb,
                                      Cf, sCfb, ldcf, Cm);
  };
  auto conv = [&](const unsigned short* Xt, int CI, const unsigned short* W9,
                  const float* bias, unsigned short* Cb, int relu,
                  float* Cf, const float* addT, int rnd) {
    gemm_conv<<<dim3(CV / 128, N / 128, B), blk, 0, stream>>>(
        Xt, CI, W9, CV, bias, Cb, relu, Cf, addT, rnd);
  };

  // 0) fp32 -> bf16 conversions (weights, v2) + conv weight prepacks
  cvt(f_w, fwB, CQK * CQK);
  cvt(g_w, gwB, CQK * CQK);
  cvt(fp_w, fpwB, DP * CQK);
  cvt(gp_w, gpwB, DP * CQK);
  cvt(h_w, hwB, CV * CV);
  cvt(v2, v2b, B * CV * N);
  prepw(sp_g_w, spgW9, CV, NH);
  prepw(sp_b_w, spbW9, CV, NH);
  prepw(r1_w, r1W9, CV, CV);
  prepw(r2_w, r2W9, CV, CV);

  // 1) normalized-q/k + pos concat, (n,c) bf16 (into cor-region overlay),
  //    coalesced: colnorm (column 1/(||.||+eps)) then LDS-transpose build
  colnorm<<<dim3(128, B), blk, 0, stream>>>(q, rnormQ);
  colnorm<<<dim3(128, B), blk, 0, stream>>>(k, rnormK);
  build_qk3<<<dim3(64, 5, B), blk, 0, stream>>>(q, pos, rnormQ, query_t);
  build_qk3<<<dim3(64, 5, B), blk, 0, stream>>>(k, pos, rnormK, keyt_t);
  // 2) v -> (n,c) bf16
  transpose_c<<<dim3(64, 4, B), blk, 0, stream>>>(v, v_t, CV);

  // 3) conv1x1 projections (weights are B^T naturally)
  gemm(query_t, (long long)N * CQK, CQK, fwB, 0, CQK, N, CQK, CQK, 1.f, f_b, 1,
       qf_t, (long long)N * CQK, CQK, nullptr, 0, 0, nullptr);
  gemm(keyt_t, (long long)N * CQK, CQK, gwB, 0, CQK, N, CQK, CQK, 1.f, g_b, 1,
       kf_t, (long long)N * CQK, CQK, nullptr, 0, 0, nullptr);
  gemm(query_t, (long long)N * CQK, CQK, fpwB, 0, CQK, N, DP, CQK, 1.f, fp_b, 1,
       qp_t, (long long)N * DP, DP, nullptr, 0, 0, nullptr);
  gemm(keyt_t, (long long)N * CQK, CQK, gpwB, 0, CQK, N, DP, CQK, 1.f, gp_b, 1,
       kp_t, (long long)N * DP, DP, nullptr, 0, 0, nullptr);
  // vh = h_w @ v : (c,n) bf16, bias per row
  gemm(hwB, 0, CV, v_t, (long long)N * CV, CV, CV, N, CV, 1.f, h_b, 2,
       vh, (long long)CV * N, N, nullptr, 0, 0, nullptr);

  // 4) cor = Q K^T / sqrt(320) -> fp32 into d_out (overlay now dead)
  gemm(qf_t, (long long)N * CQK, CQK, kf_t, (long long)N * CQK, CQK, N, N, CQK,
       INV_SQRT_CQK, nullptr, 0, nullptr, 0, 0,
       cor_o, (long long)N * N, N, nullptr);
  // 5) mask bits = (Qp Kp^T > 0)
  gemm(qp_t, (long long)N * DP, DP, kp_t, (long long)N * DP, DP, N, N, DP, 1.f,
       nullptr, 0, nullptr, 0, 0, nullptr, 0, 0, maskB16);

  // 6) per-row softmax stats + conf
  stats_rows<<<dim3(B * N), blk, 0, stream>>>(cor_o, (const unsigned char*)maskB16,
                                              statA, confF);
  // 7+8) fused: out = (softmax(cor)*mask) @ V -> (n,c) fp32 (res overlay);
  //      out2 = softmax(mask ? -1e4 : cor) @ V2 -> (c,n) fp32 output
  gemm_pv5<<<dim3(128, 2 * B), blk, 0, stream>>>(
      cor_o, (const unsigned char*)maskB16, statA, vh, v2b, outBuf, out2_o);

  // 9) SPADE branch: tiny seg conv direct fp32; gamma/beta convs as MFMA GEMM
  inorm_stats<<<dim3(CV, B), blk, 0, stream>>>(q, muF, rsF);
  conv3x3<<<dim3(16, NH, B), blk, 0, stream>>>(seg, sp_s_w, sp_s_b, IC, NH, nullptr, actv, 1, 0);
  transpose_c<<<dim3(64, 2, B), blk, 0, stream>>>(actv, actvT, NH);
  conv(actvT, NH, spgW9, sp_g_b, nullptr, 0, gC, nullptr, 0);
  conv(actvT, NH, spbW9, sp_b_b, nullptr, 0, bC, nullptr, 0);
  // 10) pono (emits yF fp32 (c,n) + yT bf16 (n,c))
  pono_y<<<dim3(N, B), blk, 0, stream>>>(outBuf, confF, gC, bC, q, muF, rsF, yF, yT);
  // 11) residual convs as MFMA GEMMs:
  //     a1T = relu(conv(yT)) bf16 (n,c);  res = conv(a1T) + yF, bf16-rounded
  conv(yT, CV, r1W9, r1_b, a1T, 1, nullptr, nullptr, 0);
  conv(a1T, CV, r2W9, r2_b, nullptr, 0, res_o, yF, 1);
}

// Round 7
// 738.084 us; speedup vs baseline: 1.1495x; 1.1495x over previous
//
#include <hip/hip_runtime.h>
#include <stdint.h>

// ---------------------------------------------------------------------------
// DynamicTransformerBlock. I/O = FP32 (per reference dtypes); MFMA math in
// bf16 with fp32 accum; norms in fp32. 3x3 convs (except tiny CI=3 seg conv)
// are implicit-GEMM MFMA: K = 9*CI, A = shifted pixel-major bf16 input,
// B^T = prepacked bf16 weights [o][tap][ci].
// B=2, CV=256, CPOS=64, CQK=320, DP=64, H=W=64, N=4096, IC=3, NH=128
// Outputs (concat, fp32): res (2,256,64,64) | out2 (2,256,64,64) | cor (2,4096,4096)
// All outputs written bf16-rounded. Workspace ~62 MB. d_out overlays: cor
// region hosts query/key bf16 concat until the cor GEMM runs; res region
// hosts pre-pono `out` until the final conv.
// gemm_pv4 (proven 124.6us): both softmax-V GEMMs, n-tile=256, each cor
// element exp'd once per mode, cvt_pk pack, epilogue 1/sum scale.
// gemm_conv2: 64x128 tiles -> 256 blocks (r-convs) / 512 (merged SPADE
// gamma+beta pair, CO=512 concat weights, A staged once).
// ---------------------------------------------------------------------------

#define DEV static __device__ __forceinline__

typedef short short8 __attribute__((ext_vector_type(8)));
typedef float floatx4 __attribute__((ext_vector_type(4)));

DEV float bf2f(unsigned short b) { return __uint_as_float(((unsigned int)b) << 16); }
DEV unsigned short f2bf(float f) {
  unsigned int u = __float_as_uint(f);
  u += 0x7FFFu + ((u >> 16) & 1u);   // RNE
  return (unsigned short)(u >> 16);
}
DEV float bfround(float f) { return bf2f(f2bf(f)); }

// ---------------------------------------------------------------------------
// flat fp32 -> bf16 convert
// ---------------------------------------------------------------------------
__global__ __launch_bounds__(256)
void cvt_f2b(const float* __restrict__ in, unsigned short* __restrict__ out, int n)
{
  int i = blockIdx.x * 256 + threadIdx.x;
  if (i < n) out[i] = f2bf(in[i]);
}

// ---------------------------------------------------------------------------
// conv weight prepack: fp32 (CO, CI, 3, 3) -> bf16 [o][tap][ci] (K-contig)
// ---------------------------------------------------------------------------
__global__ __launch_bounds__(256)
void prep_w9(const float* __restrict__ w, unsigned short* __restrict__ w9,
             int CO, int CI)
{
  int i = blockIdx.x * 256 + threadIdx.x;
  int tot = CO * CI * 9;
  if (i >= tot) return;
  int s = i % 9, rest = i / 9;
  int ci = rest % CI, o = rest / CI;
  w9[(long long)o * 9 * CI + s * CI + ci] = f2bf(w[i]);
}

// ---------------------------------------------------------------------------
// column sumsq -> 1/(||col||+eps). x (b,256,4096). grid (128, B), block 256.
// ---------------------------------------------------------------------------
__global__ __launch_bounds__(256)
void colnorm(const float* __restrict__ x, float* __restrict__ rnorm)
{
  int b = blockIdx.y, t = threadIdx.x;
  int n = (blockIdx.x << 5) + (t & 31);
  int cg = t >> 5;
  const float* base = x + ((long long)b << 20) + n;
  float s = 0.f;
#pragma unroll
  for (int c8 = 0; c8 < 32; c8++) {
    float v = base[((long long)(cg * 32 + c8)) << 12];
    s += v * v;
  }
  __shared__ float red[256];
  red[t] = s; __syncthreads();
  for (int st = 128; st >= 32; st >>= 1) {
    if (t < st) red[t] += red[t + st];
    __syncthreads();
  }
  if (t < 32)
    rnorm[(b << 12) + n] = 1.f / (sqrtf(red[t]) + 2.2204460492503131e-16f);
}

// ---------------------------------------------------------------------------
// build query/key via LDS transpose: qt (b, n, 320) bf16 =
//   [ x[c][n] * rnorm[n] (c<256) , pos[c][n] (64) ]
// grid (64, 5, B): by<4 -> x channel-tile by*64, by==4 -> pos tile. block 256.
// ---------------------------------------------------------------------------
__global__ __launch_bounds__(256)
void build_qk3(const float* __restrict__ x, const float* __restrict__ pos,
               const float* __restrict__ rnorm, unsigned short* __restrict__ qt)
{
  __shared__ float tile[64][65];
  int b = blockIdx.z, by = blockIdx.y;
  int n0 = blockIdx.x << 6;
  int tx = threadIdx.x & 63, tg = threadIdx.x >> 6;
  const float* ib;
  int c0;
  if (by < 4) { ib = x + ((long long)b << 20) + ((long long)(by << 6) << 12); c0 = by << 6; }
  else        { ib = pos; c0 = 256; }
#pragma unroll
  for (int i = 0; i < 16; i++) {
    int r = tg * 16 + i;
    tile[r][tx] = ib[((long long)r << 12) + n0 + tx];
  }
  __syncthreads();
#pragma unroll
  for (int i = 0; i < 16; i++) {
    int r = tg * 16 + i;   // column n0+r
    float sc = (by < 4) ? rnorm[(b << 12) + n0 + r] : 1.f;
    qt[((long long)(b * 4096 + n0 + r)) * 320 + c0 + tx] = f2bf(tile[tx][r] * sc);
  }
}

// ---------------------------------------------------------------------------
// fp32 (b,C,4096) -> bf16 (b,4096,C) transpose. grid (64, C/64, B), block 256
// ---------------------------------------------------------------------------
__global__ __launch_bounds__(256)
void transpose_c(const float* __restrict__ in, unsigned short* __restrict__ out, int C)
{
  __shared__ float tile[64][65];
  int b = blockIdx.z;
  int c0 = blockIdx.y << 6;
  int n0 = blockIdx.x << 6;
  const float* ib = in + (long long)b * C * 4096;
  unsigned short* ob = out + (long long)b * C * 4096;
  int tx = threadIdx.x & 63, tg = threadIdx.x >> 6;
#pragma unroll
  for (int i = 0; i < 16; i++) {
    int r = tg * 16 + i;
    tile[r][tx] = ib[((long long)(c0 + r) << 12) + n0 + tx];
  }
  __syncthreads();
#pragma unroll
  for (int i = 0; i < 16; i++) {
    int r = tg * 16 + i;
    ob[(long long)(n0 + r) * C + c0 + tx] = f2bf(tile[tx][r]);
  }
}

// ---------------------------------------------------------------------------
// MFMA GEMM:  C[M,N] = alpha * A(M,K) * Bt(N,K)^T (+bias). A,Bt bf16
// K-contiguous. M%128==0, K%32==0, N guarded. Outputs: Cb bf16; Cf fp32
// (bf16-rounded, used for cor); Cm bit-packed sign mask (ballot).
// block 256 = 4 waves (2x2), wave tile 64x64 via 4x4 of 16x16x32 MFMA.
// ---------------------------------------------------------------------------
__global__ __launch_bounds__(256)
void gemm_bt(const unsigned short* __restrict__ A, long long sAb, int lda,
             const unsigned short* __restrict__ Bt, long long sBb, int ldb,
             int Ncols, int K, float alpha,
             const float* __restrict__ bias, int biasMode,
             unsigned short* __restrict__ Cb, long long sCbb, int ldcb,
             float* __restrict__ Cf, long long sCfb, int ldcf,
             unsigned short* __restrict__ Cm)
{
  __shared__ unsigned short As[128][40];
  __shared__ unsigned short Bs[128][40];
  int bz = blockIdx.z;
  const unsigned short* Ab = A + bz * sAb;
  const unsigned short* Bb = Bt + bz * sBb;
  int m0 = blockIdx.y << 7, n0 = blockIdx.x << 7;
  int t = threadIdx.x;
  int lane = t & 63, wave = t >> 6, quad = lane >> 4, l16 = lane & 15;
  int wm = (wave >> 1) << 6, wn = (wave & 1) << 6;

  floatx4 acc[4][4] = {};

  for (int k0 = 0; k0 < K; k0 += 32) {
#pragma unroll
    for (int s = 0; s < 2; s++) {
      int idx = t + (s << 8);
      int row = idx >> 2, ch = (idx & 3) << 3;
      short8 av = *(const short8*)(Ab + (long long)(m0 + row) * lda + k0 + ch);
      *(short8*)&As[row][ch] = av;
      short8 bv = {};
      if (n0 + row < Ncols) bv = *(const short8*)(Bb + (long long)(n0 + row) * ldb + k0 + ch);
      *(short8*)&Bs[row][ch] = bv;
    }
    __syncthreads();
    short8 af[4], bfv[4];
#pragma unroll
    for (int i = 0; i < 4; i++) af[i] = *(const short8*)&As[wm + (i << 4) + l16][quad << 3];
#pragma unroll
    for (int j = 0; j < 4; j++) bfv[j] = *(const short8*)&Bs[wn + (j << 4) + l16][quad << 3];
#pragma unroll
    for (int i = 0; i < 4; i++)
#pragma unroll
      for (int j = 0; j < 4; j++)
        acc[i][j] = __builtin_amdgcn_mfma_f32_16x16x32_bf16(af[i], bfv[j], acc[i][j], 0, 0, 0);
    __syncthreads();
  }

#pragma unroll
  for (int j = 0; j < 4; j++) {
    int col = n0 + wn + (j << 4) + l16;
    if (col >= Ncols) continue;
    float bcol = (biasMode == 1) ? bias[col] : 0.f;
#pragma unroll
    for (int i = 0; i < 4; i++) {
#pragma unroll
      for (int r = 0; r < 4; r++) {
        int row = m0 + wm + (i << 4) + (quad << 2) + r;
        float vv = acc[i][j][r] * alpha + bcol;
        if (biasMode == 2) vv += bias[row];
        if (Cb) Cb[bz * sCbb + (long long)row * ldcb + col] = f2bf(vv);
        if (Cf) Cf[bz * sCfb + (long long)row * ldcf + col] = bfround(vv);
        if (Cm) {  // only used with Ncols=4096 (no divergent continue above)
          unsigned long long bal = __ballot(vv > 0.f);
          if (l16 == 0)
            Cm[(long long)bz * 4096 * 256 + (long long)row * 256 + ((n0 + wn + (j << 4)) >> 4)]
              = (unsigned short)(bal >> (quad << 4));
        }
      }
    }
  }
}

// ---------------------------------------------------------------------------
// Implicit-GEMM 3x3 SAME conv, MFMA bf16. 64x128 tiles (2x block count of
// the old 128x128 version -> fills all 256 CUs).
//   C[pixel, o] = sum_{tap, ci} Xt[shift_tap(pixel), ci] * W9[o][tap][ci] + b[o]
// Xt: (bz, 4096, CI) bf16 pixel-major; W9: (CO, 9*CI) bf16 (CO may be 512 =
// two concatenated 256-channel convs sharing the same input).
// Outputs: Cb bf16 (n, CO) [opt relu]; Cf fp32 (c&255, n) [opt +addT, opt
// bf16-round]; cols >=256 go to Cf2 (merged-pair second output).
// grid (CO/128, 64, B), block 256. 64x64 image, SAME pad.
// ---------------------------------------------------------------------------
__global__ __launch_bounds__(256)
void gemm_conv2(const unsigned short* __restrict__ Xt, int CI,
                const unsigned short* __restrict__ W9, int CO,
                const float* __restrict__ bias,
                unsigned short* __restrict__ Cb, int relu,
                float* __restrict__ Cf, const float* __restrict__ addT, int rnd,
                float* __restrict__ Cf2)
{
  __shared__ unsigned short As[64][40];
  __shared__ unsigned short Bs[128][40];
  int bz = blockIdx.z;
  const unsigned short* Xb = Xt + (long long)bz * 4096 * CI;
  int m0 = blockIdx.y << 6, n0 = blockIdx.x << 7;
  int t = threadIdx.x;
  int lane = t & 63, wave = t >> 6, quad = lane >> 4, l16 = lane & 15;
  int wm = (wave >> 1) << 5, wn = (wave & 1) << 6;
  int K9 = 9 * CI;

  floatx4 acc[2][4] = {};

  for (int tap = 0; tap < 9; ++tap) {
    int dy = tap / 3 - 1, dx = tap % 3 - 1;
    int off = dy * 64 + dx;
    for (int kc = 0; kc < CI; kc += 32) {
      // A: 64 rows x 4 chunks = 256 slots (1/thread)
      {
        int row = t >> 2, ch = (t & 3) << 3;
        int p = m0 + row;                       // pixel in [0,4096)
        int y = (p >> 6) + dy, x = (p & 63) + dx;
        short8 av = {};
        if ((unsigned)y < 64u && (unsigned)x < 64u)
          av = *(const short8*)(Xb + (long long)(p + off) * CI + kc + ch);
        *(short8*)&As[row][ch] = av;
      }
      // B: 128 rows x 4 chunks = 512 slots (2/thread); CO multiple of 128
#pragma unroll
      for (int s = 0; s < 2; s++) {
        int idx = t + (s << 8);
        int row = idx >> 2, ch = (idx & 3) << 3;
        short8 bv = *(const short8*)(W9 + (long long)(n0 + row) * K9 + tap * CI + kc + ch);
        *(short8*)&Bs[row][ch] = bv;
      }
      __syncthreads();
      short8 af[2], bfv[4];
#pragma unroll
      for (int i = 0; i < 2; i++) af[i] = *(const short8*)&As[wm + (i << 4) + l16][quad << 3];
#pragma unroll
      for (int j = 0; j < 4; j++) bfv[j] = *(const short8*)&Bs[wn + (j << 4) + l16][quad << 3];
#pragma unroll
      for (int i = 0; i < 2; i++)
#pragma unroll
        for (int j = 0; j < 4; j++)
          acc[i][j] = __builtin_amdgcn_mfma_f32_16x16x32_bf16(af[i], bfv[j], acc[i][j], 0, 0, 0);
      __syncthreads();
    }
  }

#pragma unroll
  for (int j = 0; j < 4; j++) {
    int col = n0 + wn + (j << 4) + l16;        // output channel (may be >=256)
    float bcol = bias[col];
#pragma unroll
    for (int i = 0; i < 2; i++) {
#pragma unroll
      for (int r = 0; r < 4; r++) {
        int row = m0 + wm + (i << 4) + (quad << 2) + r;   // pixel
        float vv = acc[i][j][r] + bcol;
        if (relu) vv = fmaxf(vv, 0.f);
        if (Cb) Cb[((long long)bz * 4096 + row) * CO + col] = f2bf(vv);
        if (Cf) {
          long long oi = (((long long)bz * 256 + (col & 255)) << 12) + row;
          float ov = vv;
          if (addT) ov += addT[oi];
          float* dst = (col < 256) ? Cf : Cf2;
          dst[oi] = rnd ? bfround(ov) : ov;
        }
      }
    }
  }
}

// ---------------------------------------------------------------------------
// direct 3x3 SAME conv, fp32 in/out, weights (fp32) in LDS.
// grid (16, CO, B), block 256 (4 rows). Only used for the tiny CI=3 seg conv.
// ---------------------------------------------------------------------------
__global__ __launch_bounds__(256)
void conv3x3(const float* __restrict__ inF,
             const float* __restrict__ wgt, const float* __restrict__ bias,
             int CI, int CO, const float* __restrict__ addF,
             float* __restrict__ outF, int relu, int rnd)
{
  __shared__ float wsm[2304];
  int b = blockIdx.z, o = blockIdx.y, t = threadIdx.x;
  for (int i = t; i < CI * 9; i += 256) wsm[i] = wgt[(long long)o * CI * 9 + i];
  __syncthreads();
  int x = t & 63, y = (blockIdx.x << 2) + (t >> 6);
  bool ym = y > 0, yp = y < 63, xm = x > 0, xp = x < 63;
  int p = y * 64 + x;
  long long ibase = ((long long)b * CI) << 12;
  float acc = bias[o];
  for (int ci = 0; ci < CI; ci++) {
    const float* wp = &wsm[ci * 9];
    long long ib = ibase + ((long long)ci << 12) + p;
    float v00 = (ym && xm) ? inF[ib - 65] : 0.f;
    float v01 = ym ? inF[ib - 64] : 0.f;
    float v02 = (ym && xp) ? inF[ib - 63] : 0.f;
    float v10 = xm ? inF[ib - 1] : 0.f;
    float v11 = inF[ib];
    float v12 = xp ? inF[ib + 1] : 0.f;
    float v20 = (yp && xm) ? inF[ib + 63] : 0.f;
    float v21 = yp ? inF[ib + 64] : 0.f;
    float v22 = (yp && xp) ? inF[ib + 65] : 0.f;
    acc += v00 * wp[0] + v01 * wp[1] + v02 * wp[2]
         + v10 * wp[3] + v11 * wp[4] + v12 * wp[5]
         + v20 * wp[6] + v21 * wp[7] + v22 * wp[8];
  }
  if (relu) acc = fmaxf(acc, 0.f);
  long long oidx = (((long long)(b * CO + o)) << 12) + p;
  if (addF) acc += addF[oidx];
  outF[oidx] = rnd ? bfround(acc) : acc;
}

// ---------------------------------------------------------------------------
// Per-row softmax stats over fp32 cor (4096/row). grid 8192, block 256.
// statA[row] = {rmax1, 1/sum1, rmax2, 1/sum2};  confF[row] = conf.
// ---------------------------------------------------------------------------
__global__ __launch_bounds__(256)
void stats_rows(const float* __restrict__ corF,
                const unsigned char* __restrict__ mbits,
                float4* __restrict__ statA, float* __restrict__ confF)
{
  long long row = blockIdx.x;
  const float4* cr = (const float4*)(corF + (row << 12));
  const unsigned char* mr = mbits + row * 512;
  int t = threadIdx.x;

  float lg[16]; unsigned int mk[16];
#pragma unroll
  for (int i = 0; i < 4; i++) {
    float4 cc = cr[i * 256 + t];
    unsigned char mb = mr[(i * 256 + t) >> 1];
    int sh = (t & 1) << 2;
    lg[4 * i + 0] = cc.x; lg[4 * i + 1] = cc.y;
    lg[4 * i + 2] = cc.z; lg[4 * i + 3] = cc.w;
#pragma unroll
    for (int j = 0; j < 4; j++) mk[4 * i + j] = (mb >> (sh + j)) & 1u;
  }
  float m1 = -3.0e38f, m2 = -3.0e38f; int cnt = 0;
#pragma unroll
  for (int e = 0; e < 16; e++) {
    m1 = fmaxf(m1, lg[e]);
    if (!mk[e]) m2 = fmaxf(m2, lg[e]);
    cnt += (int)mk[e];
  }
  __shared__ float4 red4[256];
  red4[t] = make_float4(m1, m2, 0.f, 0.f); __syncthreads();
  for (int s = 128; s > 0; s >>= 1) {
    if (t < s) {
      red4[t].x = fmaxf(red4[t].x, red4[t + s].x);
      red4[t].y = fmaxf(red4[t].y, red4[t + s].y);
    }
    __syncthreads();
  }
  float rmax1 = red4[0].x;
  float rmax2 = fmaxf(red4[0].y, -10000.f);
  __syncthreads();

  float s1 = 0.f, cn = 0.f, s2 = 0.f;
#pragma unroll
  for (int e = 0; e < 16; e++) {
    float ex = __expf(fminf(lg[e] - rmax1, 0.f));
    s1 += ex;
    if (mk[e]) cn += ex;
    else s2 += __expf(fminf(lg[e] - rmax2, 0.f));
  }
  red4[t] = make_float4(s1, cn, s2, (float)cnt); __syncthreads();
  for (int s = 128; s > 0; s >>= 1) {
    if (t < s) {
      red4[t].x += red4[t + s].x; red4[t].y += red4[t + s].y;
      red4[t].z += red4[t + s].z; red4[t].w += red4[t + s].w;
    }
    __syncthreads();
  }
  if (t == 0) {
    float4 r = red4[0];
    float sum2 = r.z + r.w * __expf(fminf(-10000.f - rmax2, 0.f));
    statA[row] = make_float4(rmax1, 1.f / fmaxf(r.x, 1e-30f),
                             rmax2, 1.f / fmaxf(sum2, 1e-30f));
    confF[row] = r.y / fmaxf(r.x, 1e-30f);
  }
}

// ---------------------------------------------------------------------------
// Fused P·V GEMM, both modes in one dispatch (mode = blockIdx.y>>1).
// P reconstructed in-register from fp32 cor + bit mask + per-row stats.
// mode 0: P = mask ? exp(cor-rm1) : 0         (epilogue x 1/sum1) -> Cf0 (n,c)
// mode 1: P = mask ? exp(-1e4-rm2) : exp(cor-rm2)  (x 1/sum2)     -> Cf1 (c,n)
// Tile 32(rows) x 256(ALL cols): each cor element exp'd exactly once per
// mode. Block 256 = 4 n-waves, wave tile 32x64 = 2x4 MFMA. Grid (128, 2B)
// = 512 blocks. Reg-staged prefetch; bf16 pack via v_cvt_pk_bf16_f32.
// [proven 124.6us in R4 profile; pv5's direct-B variant regressed -> reverted]
// ---------------------------------------------------------------------------
__global__ __launch_bounds__(256, 2)
void gemm_pv4(const float* __restrict__ corF,
              const unsigned char* __restrict__ mbits,
              const float4* __restrict__ statA,
              const unsigned short* __restrict__ Bt0,
              const unsigned short* __restrict__ Bt1,
              float* __restrict__ Cf0, float* __restrict__ Cf1)
{
  __shared__ unsigned short As[32][40];
  __shared__ unsigned short Bs[256][40];
  __shared__ float2 sstat[32];           // (-rm*log2e, iv) per A row
  int bz = blockIdx.y & 1, mode = blockIdx.y >> 1;
  const float* corb = corF + (long long)bz * 4096 * 4096;
  const unsigned char* mbb = mbits + (long long)bz * 4096 * 512;
  const unsigned short* Bb = (mode ? Bt1 : Bt0) + (long long)bz * 256 * 4096;
  int m0 = blockIdx.x << 5;
  int t = threadIdx.x;
  int lane = t & 63, wave = t >> 6, quad = lane >> 4, l16 = lane & 15;
  int wn = wave << 6;
  const float L2E = 1.44269504088896340736f;

  if (t < 32) {
    float4 s = statA[(long long)bz * 4096 + m0 + t];
    float rm = mode ? s.z : s.x, iv = mode ? s.w : s.y;
    sstat[t] = make_float2(-rm * L2E, iv);
  }
  __syncthreads();

  // A: row rA (32 rows), 4-float k-chunk cA; B: rows rB+{0,64,128,192}, chunk cB
  int rA = t >> 3, cA = (t & 7) << 2;
  int rB = t >> 2, cB = (t & 3) << 3;
  float nrmL = sstat[rA].x;                       // -rm*log2e
  float mvr = exp2f(-10000.f * L2E + nrmL);      // mode1 masked value (<=1)

  floatx4 acc[2][4] = {};

  const float* cpb = corb + (long long)(m0 + rA) * 4096 + cA;
  const unsigned char* mbp = mbb + (long long)(m0 + rA) * 512;
  const unsigned short* pbb = Bb + (long long)rB * 4096 + cB;

  float4 pa; short8 pb[4]; unsigned int pmk;
  auto issue = [&](int kk) {
    pa = *(const float4*)(cpb + kk);
    pmk = (unsigned int)(mbp[(kk + cA) >> 3] >> (cA & 7)) & 0xFu;  // 4 bits
#pragma unroll
    for (int j = 0; j < 4; j++)
      pb[j] = *(const short8*)(pbb + (long long)(j << 6) * 4096 + kk);
  };

  issue(0);
  for (int k0 = 0; k0 < 4096; k0 += 32) {
    // commit prefetched tile to LDS (A -> unnormalized P in bf16)
    {
      float cs[4] = {pa.x, pa.y, pa.z, pa.w};
      float vs[4];
#pragma unroll
      for (int j = 0; j < 4; j++) {
        float e = exp2f(fmaf(cs[j], L2E, nrmL));   // exp(c - rm)
        bool mk = (pmk >> j) & 1u;
        vs[j] = mode ? (mk ? mvr : e) : (mk ? e : 0.f);
      }
      unsigned int u01, u23;
      asm("v_cvt_pk_bf16_f32 %0, %1, %2" : "=v"(u01) : "v"(vs[0]), "v"(vs[1]));
      asm("v_cvt_pk_bf16_f32 %0, %1, %2" : "=v"(u23) : "v"(vs[2]), "v"(vs[3]));
      *(unsigned int*)&As[rA][cA] = u01;
      *(unsigned int*)&As[rA][cA + 2] = u23;
#pragma unroll
      for (int j = 0; j < 4; j++)
        *(short8*)&Bs[rB + (j << 6)][cB] = pb[j];
    }
    __syncthreads();
    if (k0 + 32 < 4096) issue(k0 + 32);   // hide HBM latency under MFMA phase
    short8 af[2], bfv[4];
#pragma unroll
    for (int i = 0; i < 2; i++) af[i] = *(const short8*)&As[(i << 4) + l16][quad << 3];
#pragma unroll
    for (int j = 0; j < 4; j++) bfv[j] = *(const short8*)&Bs[wn + (j << 4) + l16][quad << 3];
#pragma unroll
    for (int i = 0; i < 2; i++)
#pragma unroll
      for (int j = 0; j < 4; j++)
        acc[i][j] = __builtin_amdgcn_mfma_f32_16x16x32_bf16(af[i], bfv[j], acc[i][j], 0, 0, 0);
    __syncthreads();
  }

#pragma unroll
  for (int j = 0; j < 4; j++) {
    int col = wn + (j << 4) + l16;        // c index < 256
#pragma unroll
    for (int i = 0; i < 2; i++) {
#pragma unroll
      for (int r = 0; r < 4; r++) {
        int lrow = (i << 4) + (quad << 2) + r;
        int row = m0 + lrow;
        float vv = bfround(acc[i][j][r] * sstat[lrow].y);   // x 1/sum
        if (mode) Cf1[(long long)bz * 256 * 4096 + (long long)col * 4096 + row] = vv;
        else      Cf0[(long long)bz * 4096 * 256 + (long long)row * 256 + col] = vv;
      }
    }
  }
}

// ---------------------------------------------------------------------------
// instance-norm stats of q (fp32) over spatial. grid (256, 2), block 256.
// ---------------------------------------------------------------------------
__global__ __launch_bounds__(256)
void inorm_stats(const float* __restrict__ q, float* __restrict__ mu, float* __restrict__ rs)
{
  int c = blockIdx.x, b = blockIdx.y, t = threadIdx.x;
  const float* base = q + ((long long)(b * 256 + c) << 12);
  float s = 0.f, s2 = 0.f;
  for (int i = t; i < 4096; i += 256) { float v = base[i]; s += v; s2 += v * v; }
  __shared__ float r1[256], r2[256];
  r1[t] = s; r2[t] = s2; __syncthreads();
  for (int st = 128; st > 0; st >>= 1) {
    if (t < st) { r1[t] += r1[t + st]; r2[t] += r2[t + st]; }
    __syncthreads();
  }
  if (t == 0) {
    float m = r1[0] * (1.f / 4096.f);
    float var = fmaxf(r2[0] * (1.f / 4096.f) - m * m, 0.f);
    mu[b * 256 + c] = m;
    rs[b * 256 + c] = rsqrtf(var + 1e-5f);
  }
}

// ---------------------------------------------------------------------------
// pono epilogue: t = out + (1-conf)*spade + q; y = channel-norm(t). fp32 (c,n).
// Also emits y transposed as bf16 (n,c) for the residual conv GEMMs.
// grid (4096, 2), block 256 (thread = channel)
// ---------------------------------------------------------------------------
__global__ __launch_bounds__(256)
void pono_y(const float* __restrict__ outF, const float* __restrict__ confF,
            const float* __restrict__ gF, const float* __restrict__ bF,
            const float* __restrict__ q, const float* __restrict__ mu,
            const float* __restrict__ rs, float* __restrict__ yF,
            unsigned short* __restrict__ yT)
{
  int n = blockIdx.x, b = blockIdx.y, c = threadIdx.x;
  long long cn = ((long long)(b * 256 + c) << 12) + n;
  float qv = q[cn];
  float sp = (qv - mu[b * 256 + c]) * rs[b * 256 + c] * (1.f + gF[cn]) + bF[cn];
  float cf = confF[b * 4096 + n];
  float tv = outF[((long long)(b * 4096 + n) << 8) + c] + (1.f - cf) * sp + qv;
  __shared__ float red[256];
  red[c] = tv; __syncthreads();
  for (int s = 128; s > 0; s >>= 1) { if (c < s) red[c] += red[c + s]; __syncthreads(); }
  float m = red[0] * (1.f / 256.f); __syncthreads();
  float d = tv - m;
  red[c] = d * d; __syncthreads();
  for (int s = 128; s > 0; s >>= 1) { if (c < s) red[c] += red[c + s]; __syncthreads(); }
  float var = fmaxf(red[0] * (1.f / 256.f), 0.f);
  float yv = d * rsqrtf(var + 1e-5f);
  yF[cn] = yv;
  yT[((long long)(b * 4096 + n) << 8) + c] = f2bf(yv);
}

// ---------------------------------------------------------------------------

extern "C" void kernel_launch(void* const* d_in, const int* in_sizes, int n_in,
                              void* d_out, int out_size, void* d_ws, size_t ws_size,
                              hipStream_t stream)
{
  (void)in_sizes; (void)n_in; (void)out_size; (void)ws_size;
  const int B = 2, CV = 256, CQK = 320, DP = 64, N = 4096, NH = 128, IC = 3;
  const float INV_SQRT_CQK = 0.05590169943749474241f;  // 1/sqrt(320)

  const float* q    = (const float*)d_in[0];
  const float* k    = (const float*)d_in[1];
  const float* v    = (const float*)d_in[2];
  const float* pos  = (const float*)d_in[3];
  const float* seg  = (const float*)d_in[4];
  const float* v2   = (const float*)d_in[5];
  const float* f_w  = (const float*)d_in[6];
  const float* f_b  = (const float*)d_in[7];
  const float* g_w  = (const float*)d_in[8];
  const float* g_b  = (const float*)d_in[9];
  const float* h_w  = (const float*)d_in[10];
  const float* h_b  = (const float*)d_in[11];
  const float* fp_w = (const float*)d_in[12];
  const float* fp_b = (const float*)d_in[13];
  const float* gp_w = (const float*)d_in[14];
  const float* gp_b = (const float*)d_in[15];
  const float* sp_s_w = (const float*)d_in[16];
  const float* sp_s_b = (const float*)d_in[17];
  const float* sp_g_w = (const float*)d_in[18];
  const float* sp_g_b = (const float*)d_in[19];
  const float* sp_b_w = (const float*)d_in[20];
  const float* sp_b_b = (const float*)d_in[21];
  const float* r1_w = (const float*)d_in[22];
  const float* r1_b = (const float*)d_in[23];
  const float* r2_w = (const float*)d_in[24];
  const float* r2_b = (const float*)d_in[25];

  float* res_o  = (float*)d_out;
  float* out2_o = res_o + (long long)B * CV * N;
  float* cor_o  = res_o + 2ll * B * CV * N;

  // d_out overlays (dead until their real producer runs)
  unsigned short* query_t = (unsigned short*)cor_o;
  unsigned short* keyt_t  = query_t + (long long)B * N * CQK;
  float*          outBuf  = res_o;   // exactly B*N*CV floats

  // workspace carve (256B aligned), ~62 MB
  char* wp_ = (char*)d_ws;
  auto take = [&](size_t bytes) -> void* {
    void* r = wp_; wp_ += (bytes + 255) & ~(size_t)255; return r;
  };
  unsigned short* v_t     = (unsigned short*)take((size_t)B * N * CV * 2);
  unsigned short* qf_t    = (unsigned short*)take((size_t)B * N * CQK * 2);
  unsigned short* kf_t    = (unsigned short*)take((size_t)B * N * CQK * 2);
  unsigned short* qp_t    = (unsigned short*)take((size_t)B * N * DP * 2);
  unsigned short* kp_t    = (unsigned short*)take((size_t)B * N * DP * 2);
  unsigned short* vh      = (unsigned short*)take((size_t)B * CV * N * 2);
  unsigned short* v2b     = (unsigned short*)take((size_t)B * CV * N * 2);
  unsigned short* fwB     = (unsigned short*)take((size_t)CQK * CQK * 2);
  unsigned short* gwB     = (unsigned short*)take((size_t)CQK * CQK * 2);
  unsigned short* fpwB    = (unsigned short*)take((size_t)DP * CQK * 2);
  unsigned short* gpwB    = (unsigned short*)take((size_t)DP * CQK * 2);
  unsigned short* hwB     = (unsigned short*)take((size_t)CV * CV * 2);
  unsigned short* maskB16 = (unsigned short*)take((size_t)B * N * 256 * 2);
  float4*         statA   = (float4*)take((size_t)B * N * 16);
  float*          confF   = (float*)take((size_t)B * N * 4);
  float*          muF     = (float*)take((size_t)B * CV * 4);
  float*          rsF     = (float*)take((size_t)B * CV * 4);
  float*          rnormQ  = (float*)take((size_t)B * N * 4);
  float*          rnormK  = (float*)take((size_t)B * N * 4);
  float*          actv    = (float*)take((size_t)B * NH * N * 4);
  float*          gC      = (float*)take((size_t)B * CV * N * 4);
  float*          bC      = (float*)take((size_t)B * CV * N * 4);
  float*          yF      = (float*)take((size_t)B * CV * N * 4);
  // prepacked conv weights, bf16 [o][tap][ci]; SPADE gamma+beta concatenated
  unsigned short* spW9    = (unsigned short*)take((size_t)2 * CV * 9 * NH * 2);
  unsigned short* r1W9    = (unsigned short*)take((size_t)CV * 9 * CV * 2);
  unsigned short* r2W9    = (unsigned short*)take((size_t)CV * 9 * CV * 2);
  float*          spBias  = (float*)take((size_t)2 * CV * 4);
  // bf16 pixel-major conv activations — reuse regions dead by SPADE time:
  unsigned short* yT      = qf_t;   // B*N*256*2 = 4 MB  <= 5.24 MB (dead after cor GEMM)
  unsigned short* a1T     = kf_t;   // B*N*256*2 = 4 MB  <= 5.24 MB (dead after cor GEMM)
  unsigned short* actvT   = v_t;    // B*N*128*2 = 2 MB  <= 4 MB    (dead after vh GEMM)

  dim3 blk(256);
  auto cvt = [&](const float* in, unsigned short* out, int n) {
    cvt_f2b<<<dim3((n + 255) / 256), blk, 0, stream>>>(in, out, n);
  };
  auto prepw = [&](const float* w, unsigned short* w9, int CO, int CI) {
    prep_w9<<<dim3((CO * CI * 9 + 255) / 256), blk, 0, stream>>>(w, w9, CO, CI);
  };
  auto gemm = [&](const unsigned short* A, long long sAb, int lda,
                  const unsigned short* Bt, long long sBb, int ldb,
                  int M, int Nc, int K, float alpha,
                  const float* bias, int biasMode,
                  unsigned short* Cb, long long sCbb, int ldcb,
                  float* Cf, long long sCfb, int ldcf,
                  unsigned short* Cm) {
    dim3 grid((Nc + 127) / 128, M / 128, B);
    gemm_bt<<<grid, blk, 0, stream>>>(A, sAb, lda, Bt, sBb, ldb, Nc, K, alpha,
                                      bias, biasMode, Cb, sCbb, ldcb,
                                      Cf, sCfb, ldcf, Cm);
  };
  auto conv = [&](const unsigned short* Xt, int CI, const unsigned short* W9,
                  int CO, const float* bias, unsigned short* Cb, int relu,
                  float* Cf, const float* addT, int rnd, float* Cf2) {
    gemm_conv2<<<dim3(CO / 128, N / 64, B), blk, 0, stream>>>(
        Xt, CI, W9, CO, bias, Cb, relu, Cf, addT, rnd, Cf2);
  };

  // 0) fp32 -> bf16 conversions (weights, v2) + conv weight prepacks
  cvt(f_w, fwB, CQK * CQK);
  cvt(g_w, gwB, CQK * CQK);
  cvt(fp_w, fpwB, DP * CQK);
  cvt(gp_w, gpwB, DP * CQK);
  cvt(h_w, hwB, CV * CV);
  cvt(v2, v2b, B * CV * N);
  prepw(sp_g_w, spW9, CV, NH);
  prepw(sp_b_w, spW9 + (size_t)CV * 9 * NH, CV, NH);
  prepw(r1_w, r1W9, CV, CV);
  prepw(r2_w, r2W9, CV, CV);
  hipMemcpyAsync(spBias, sp_g_b, CV * sizeof(float), hipMemcpyDeviceToDevice, stream);
  hipMemcpyAsync(spBias + CV, sp_b_b, CV * sizeof(float), hipMemcpyDeviceToDevice, stream);

  // 1) normalized-q/k + pos concat, (n,c) bf16 (into cor-region overlay),
  //    coalesced: colnorm (column 1/(||.||+eps)) then LDS-transpose build
  colnorm<<<dim3(128, B), blk, 0, stream>>>(q, rnormQ);
  colnorm<<<dim3(128, B), blk, 0, stream>>>(k, rnormK);
  build_qk3<<<dim3(64, 5, B), blk, 0, stream>>>(q, pos, rnormQ, query_t);
  build_qk3<<<dim3(64, 5, B), blk, 0, stream>>>(k, pos, rnormK, keyt_t);
  // 2) v -> (n,c) bf16
  transpose_c<<<dim3(64, 4, B), blk, 0, stream>>>(v, v_t, CV);

  // 3) conv1x1 projections (weights are B^T naturally)
  gemm(query_t, (long long)N * CQK, CQK, fwB, 0, CQK, N, CQK, CQK, 1.f, f_b, 1,
       qf_t, (long long)N * CQK, CQK, nullptr, 0, 0, nullptr);
  gemm(keyt_t, (long long)N * CQK, CQK, gwB, 0, CQK, N, CQK, CQK, 1.f, g_b, 1,
       kf_t, (long long)N * CQK, CQK, nullptr, 0, 0, nullptr);
  gemm(query_t, (long long)N * CQK, CQK, fpwB, 0, CQK, N, DP, CQK, 1.f, fp_b, 1,
       qp_t, (long long)N * DP, DP, nullptr, 0, 0, nullptr);
  gemm(keyt_t, (long long)N * CQK, CQK, gpwB, 0, CQK, N, DP, CQK, 1.f, gp_b, 1,
       kp_t, (long long)N * DP, DP, nullptr, 0, 0, nullptr);
  // vh = h_w @ v : (c,n) bf16, bias per row
  gemm(hwB, 0, CV, v_t, (long long)N * CV, CV, CV, N, CV, 1.f, h_b, 2,
       vh, (long long)CV * N, N, nullptr, 0, 0, nullptr);

  // 4) cor = Q K^T / sqrt(320) -> fp32 into d_out (overlay now dead)
  gemm(qf_t, (long long)N * CQK, CQK, kf_t, (long long)N * CQK, CQK, N, N, CQK,
       INV_SQRT_CQK, nullptr, 0, nullptr, 0, 0,
       cor_o, (long long)N * N, N, nullptr);
  // 5) mask bits = (Qp Kp^T > 0)
  gemm(qp_t, (long long)N * DP, DP, kp_t, (long long)N * DP, DP, N, N, DP, 1.f,
       nullptr, 0, nullptr, 0, 0, nullptr, 0, 0, maskB16);

  // 6) per-row softmax stats + conf
  stats_rows<<<dim3(B * N), blk, 0, stream>>>(cor_o, (const unsigned char*)maskB16,
                                              statA, confF);
  // 7+8) fused: out = (softmax(cor)*mask) @ V -> (n,c) fp32 (res overlay);
  //      out2 = softmax(mask ? -1e4 : cor) @ V2 -> (c,n) fp32 output
  gemm_pv4<<<dim3(128, 2 * B), blk, 0, stream>>>(
      cor_o, (const unsigned char*)maskB16, statA, vh, v2b, outBuf, out2_o);

  // 9) SPADE branch: tiny seg conv direct fp32; gamma+beta as ONE merged
  //    512-channel MFMA conv (A staged once, 512 blocks)
  inorm_stats<<<dim3(CV, B), blk, 0, stream>>>(q, muF, rsF);
  conv3x3<<<dim3(16, NH, B), blk, 0, stream>>>(seg, sp_s_w, sp_s_b, IC, NH, nullptr, actv, 1, 0);
  transpose_c<<<dim3(64, 2, B), blk, 0, stream>>>(actv, actvT, NH);
  conv(actvT, NH, spW9, 2 * CV, spBias, nullptr, 0, gC, nullptr, 0, bC);
  // 10) pono (emits yF fp32 (c,n) + yT bf16 (n,c))
  pono_y<<<dim3(N, B), blk, 0, stream>>>(outBuf, confF, gC, bC, q, muF, rsF, yF, yT);
  // 11) residual convs as MFMA GEMMs:
  //     a1T = relu(conv(yT)) bf16 (n,c);  res = conv(a1T) + yF, bf16-rounded
  conv(yT, CV, r1W9, CV, r1_b, a1T, 1, nullptr, nullptr, 0, nullptr);
  conv(a1T, CV, r2W9, CV, r2_b, nullptr, 0, res_o, yF, 1, nullptr);
}

// Round 8
// 697.033 us; speedup vs baseline: 1.2172x; 1.0589x over previous
//
#include <hip/hip_runtime.h>
#include <stdint.h>

// ---------------------------------------------------------------------------
// DynamicTransformerBlock. I/O = FP32 (per reference dtypes); MFMA math in
// bf16 with fp32 accum; norms in fp32. 3x3 convs (except tiny CI=3 seg conv)
// are implicit-GEMM MFMA: K = 9*CI, A = shifted pixel-major bf16 input,
// B^T = prepacked bf16 weights [o][tap][ci].
// B=2, CV=256, CPOS=64, CQK=320, DP=64, H=W=64, N=4096, IC=3, NH=128
// Outputs (concat, fp32): res (2,256,64,64) | out2 (2,256,64,64) | cor (2,4096,4096)
// All outputs written bf16-rounded. Workspace ~64 MB. d_out overlays: cor
// region hosts query/key bf16 concat until the cor GEMM runs; res region
// hosts pre-pono `out` until the final conv.
// R7: gemm_pv4b = pv4 with K-step 64 (half the barrier pairs, 2x MFMA/step);
// qf+qp and kf+kp projections fused into single N=384 GEMMs (exact 3-tile,
// concat weights/bias; downstream uses lda=384 and +320 col offset).
// ---------------------------------------------------------------------------

#define DEV static __device__ __forceinline__

typedef short short8 __attribute__((ext_vector_type(8)));
typedef float floatx4 __attribute__((ext_vector_type(4)));

DEV float bf2f(unsigned short b) { return __uint_as_float(((unsigned int)b) << 16); }
DEV unsigned short f2bf(float f) {
  unsigned int u = __float_as_uint(f);
  u += 0x7FFFu + ((u >> 16) & 1u);   // RNE
  return (unsigned short)(u >> 16);
}
DEV float bfround(float f) { return bf2f(f2bf(f)); }

// ---------------------------------------------------------------------------
// flat fp32 -> bf16 convert
// ---------------------------------------------------------------------------
__global__ __launch_bounds__(256)
void cvt_f2b(const float* __restrict__ in, unsigned short* __restrict__ out, int n)
{
  int i = blockIdx.x * 256 + threadIdx.x;
  if (i < n) out[i] = f2bf(in[i]);
}

// ---------------------------------------------------------------------------
// conv weight prepack: fp32 (CO, CI, 3, 3) -> bf16 [o][tap][ci] (K-contig)
// ---------------------------------------------------------------------------
__global__ __launch_bounds__(256)
void prep_w9(const float* __restrict__ w, unsigned short* __restrict__ w9,
             int CO, int CI)
{
  int i = blockIdx.x * 256 + threadIdx.x;
  int tot = CO * CI * 9;
  if (i >= tot) return;
  int s = i % 9, rest = i / 9;
  int ci = rest % CI, o = rest / CI;
  w9[(long long)o * 9 * CI + s * CI + ci] = f2bf(w[i]);
}

// ---------------------------------------------------------------------------
// column sumsq -> 1/(||col||+eps). x (b,256,4096). grid (128, B), block 256.
// ---------------------------------------------------------------------------
__global__ __launch_bounds__(256)
void colnorm(const float* __restrict__ x, float* __restrict__ rnorm)
{
  int b = blockIdx.y, t = threadIdx.x;
  int n = (blockIdx.x << 5) + (t & 31);
  int cg = t >> 5;
  const float* base = x + ((long long)b << 20) + n;
  float s = 0.f;
#pragma unroll
  for (int c8 = 0; c8 < 32; c8++) {
    float v = base[((long long)(cg * 32 + c8)) << 12];
    s += v * v;
  }
  __shared__ float red[256];
  red[t] = s; __syncthreads();
  for (int st = 128; st >= 32; st >>= 1) {
    if (t < st) red[t] += red[t + st];
    __syncthreads();
  }
  if (t < 32)
    rnorm[(b << 12) + n] = 1.f / (sqrtf(red[t]) + 2.2204460492503131e-16f);
}

// ---------------------------------------------------------------------------
// build query/key via LDS transpose: qt (b, n, 320) bf16 =
//   [ x[c][n] * rnorm[n] (c<256) , pos[c][n] (64) ]
// grid (64, 5, B): by<4 -> x channel-tile by*64, by==4 -> pos tile. block 256.
// ---------------------------------------------------------------------------
__global__ __launch_bounds__(256)
void build_qk3(const float* __restrict__ x, const float* __restrict__ pos,
               const float* __restrict__ rnorm, unsigned short* __restrict__ qt)
{
  __shared__ float tile[64][65];
  int b = blockIdx.z, by = blockIdx.y;
  int n0 = blockIdx.x << 6;
  int tx = threadIdx.x & 63, tg = threadIdx.x >> 6;
  const float* ib;
  int c0;
  if (by < 4) { ib = x + ((long long)b << 20) + ((long long)(by << 6) << 12); c0 = by << 6; }
  else        { ib = pos; c0 = 256; }
#pragma unroll
  for (int i = 0; i < 16; i++) {
    int r = tg * 16 + i;
    tile[r][tx] = ib[((long long)r << 12) + n0 + tx];
  }
  __syncthreads();
#pragma unroll
  for (int i = 0; i < 16; i++) {
    int r = tg * 16 + i;   // column n0+r
    float sc = (by < 4) ? rnorm[(b << 12) + n0 + r] : 1.f;
    qt[((long long)(b * 4096 + n0 + r)) * 320 + c0 + tx] = f2bf(tile[tx][r] * sc);
  }
}

// ---------------------------------------------------------------------------
// fp32 (b,C,4096) -> bf16 (b,4096,C) transpose. grid (64, C/64, B), block 256
// ---------------------------------------------------------------------------
__global__ __launch_bounds__(256)
void transpose_c(const float* __restrict__ in, unsigned short* __restrict__ out, int C)
{
  __shared__ float tile[64][65];
  int b = blockIdx.z;
  int c0 = blockIdx.y << 6;
  int n0 = blockIdx.x << 6;
  const float* ib = in + (long long)b * C * 4096;
  unsigned short* ob = out + (long long)b * C * 4096;
  int tx = threadIdx.x & 63, tg = threadIdx.x >> 6;
#pragma unroll
  for (int i = 0; i < 16; i++) {
    int r = tg * 16 + i;
    tile[r][tx] = ib[((long long)(c0 + r) << 12) + n0 + tx];
  }
  __syncthreads();
#pragma unroll
  for (int i = 0; i < 16; i++) {
    int r = tg * 16 + i;
    ob[(long long)(n0 + r) * C + c0 + tx] = f2bf(tile[tx][r]);
  }
}

// ---------------------------------------------------------------------------
// MFMA GEMM:  C[M,N] = alpha * A(M,K) * Bt(N,K)^T (+bias). A,Bt bf16
// K-contiguous. M%128==0, K%32==0, N guarded. Outputs: Cb bf16; Cf fp32
// (bf16-rounded, used for cor); Cm bit-packed sign mask (ballot).
// block 256 = 4 waves (2x2), wave tile 64x64 via 4x4 of 16x16x32 MFMA.
// ---------------------------------------------------------------------------
__global__ __launch_bounds__(256)
void gemm_bt(const unsigned short* __restrict__ A, long long sAb, int lda,
             const unsigned short* __restrict__ Bt, long long sBb, int ldb,
             int Ncols, int K, float alpha,
             const float* __restrict__ bias, int biasMode,
             unsigned short* __restrict__ Cb, long long sCbb, int ldcb,
             float* __restrict__ Cf, long long sCfb, int ldcf,
             unsigned short* __restrict__ Cm)
{
  __shared__ unsigned short As[128][40];
  __shared__ unsigned short Bs[128][40];
  int bz = blockIdx.z;
  const unsigned short* Ab = A + bz * sAb;
  const unsigned short* Bb = Bt + bz * sBb;
  int m0 = blockIdx.y << 7, n0 = blockIdx.x << 7;
  int t = threadIdx.x;
  int lane = t & 63, wave = t >> 6, quad = lane >> 4, l16 = lane & 15;
  int wm = (wave >> 1) << 6, wn = (wave & 1) << 6;

  floatx4 acc[4][4] = {};

  for (int k0 = 0; k0 < K; k0 += 32) {
#pragma unroll
    for (int s = 0; s < 2; s++) {
      int idx = t + (s << 8);
      int row = idx >> 2, ch = (idx & 3) << 3;
      short8 av = *(const short8*)(Ab + (long long)(m0 + row) * lda + k0 + ch);
      *(short8*)&As[row][ch] = av;
      short8 bv = {};
      if (n0 + row < Ncols) bv = *(const short8*)(Bb + (long long)(n0 + row) * ldb + k0 + ch);
      *(short8*)&Bs[row][ch] = bv;
    }
    __syncthreads();
    short8 af[4], bfv[4];
#pragma unroll
    for (int i = 0; i < 4; i++) af[i] = *(const short8*)&As[wm + (i << 4) + l16][quad << 3];
#pragma unroll
    for (int j = 0; j < 4; j++) bfv[j] = *(const short8*)&Bs[wn + (j << 4) + l16][quad << 3];
#pragma unroll
    for (int i = 0; i < 4; i++)
#pragma unroll
      for (int j = 0; j < 4; j++)
        acc[i][j] = __builtin_amdgcn_mfma_f32_16x16x32_bf16(af[i], bfv[j], acc[i][j], 0, 0, 0);
    __syncthreads();
  }

#pragma unroll
  for (int j = 0; j < 4; j++) {
    int col = n0 + wn + (j << 4) + l16;
    if (col >= Ncols) continue;
    float bcol = (biasMode == 1) ? bias[col] : 0.f;
#pragma unroll
    for (int i = 0; i < 4; i++) {
#pragma unroll
      for (int r = 0; r < 4; r++) {
        int row = m0 + wm + (i << 4) + (quad << 2) + r;
        float vv = acc[i][j][r] * alpha + bcol;
        if (biasMode == 2) vv += bias[row];
        if (Cb) Cb[bz * sCbb + (long long)row * ldcb + col] = f2bf(vv);
        if (Cf) Cf[bz * sCfb + (long long)row * ldcf + col] = bfround(vv);
        if (Cm) {  // only used with Ncols=4096 (no divergent continue above)
          unsigned long long bal = __ballot(vv > 0.f);
          if (l16 == 0)
            Cm[(long long)bz * 4096 * 256 + (long long)row * 256 + ((n0 + wn + (j << 4)) >> 4)]
              = (unsigned short)(bal >> (quad << 4));
        }
      }
    }
  }
}

// ---------------------------------------------------------------------------
// Implicit-GEMM 3x3 SAME conv, MFMA bf16. 64x128 tiles.
// Xt: (bz, 4096, CI) bf16 pixel-major; W9: (CO, 9*CI) bf16 (CO may be 512 =
// two concatenated 256-channel convs sharing the same input).
// Outputs: Cb bf16 (n, CO) [opt relu]; Cf fp32 (c&255, n) [opt +addT, opt
// bf16-round]; cols >=256 go to Cf2. grid (CO/128, 64, B), block 256.
// ---------------------------------------------------------------------------
__global__ __launch_bounds__(256)
void gemm_conv2(const unsigned short* __restrict__ Xt, int CI,
                const unsigned short* __restrict__ W9, int CO,
                const float* __restrict__ bias,
                unsigned short* __restrict__ Cb, int relu,
                float* __restrict__ Cf, const float* __restrict__ addT, int rnd,
                float* __restrict__ Cf2)
{
  __shared__ unsigned short As[64][40];
  __shared__ unsigned short Bs[128][40];
  int bz = blockIdx.z;
  const unsigned short* Xb = Xt + (long long)bz * 4096 * CI;
  int m0 = blockIdx.y << 6, n0 = blockIdx.x << 7;
  int t = threadIdx.x;
  int lane = t & 63, wave = t >> 6, quad = lane >> 4, l16 = lane & 15;
  int wm = (wave >> 1) << 5, wn = (wave & 1) << 6;
  int K9 = 9 * CI;

  floatx4 acc[2][4] = {};

  for (int tap = 0; tap < 9; ++tap) {
    int dy = tap / 3 - 1, dx = tap % 3 - 1;
    int off = dy * 64 + dx;
    for (int kc = 0; kc < CI; kc += 32) {
      // A: 64 rows x 4 chunks = 256 slots (1/thread)
      {
        int row = t >> 2, ch = (t & 3) << 3;
        int p = m0 + row;                       // pixel in [0,4096)
        int y = (p >> 6) + dy, x = (p & 63) + dx;
        short8 av = {};
        if ((unsigned)y < 64u && (unsigned)x < 64u)
          av = *(const short8*)(Xb + (long long)(p + off) * CI + kc + ch);
        *(short8*)&As[row][ch] = av;
      }
      // B: 128 rows x 4 chunks = 512 slots (2/thread); CO multiple of 128
#pragma unroll
      for (int s = 0; s < 2; s++) {
        int idx = t + (s << 8);
        int row = idx >> 2, ch = (idx & 3) << 3;
        short8 bv = *(const short8*)(W9 + (long long)(n0 + row) * K9 + tap * CI + kc + ch);
        *(short8*)&Bs[row][ch] = bv;
      }
      __syncthreads();
      short8 af[2], bfv[4];
#pragma unroll
      for (int i = 0; i < 2; i++) af[i] = *(const short8*)&As[wm + (i << 4) + l16][quad << 3];
#pragma unroll
      for (int j = 0; j < 4; j++) bfv[j] = *(const short8*)&Bs[wn + (j << 4) + l16][quad << 3];
#pragma unroll
      for (int i = 0; i < 2; i++)
#pragma unroll
        for (int j = 0; j < 4; j++)
          acc[i][j] = __builtin_amdgcn_mfma_f32_16x16x32_bf16(af[i], bfv[j], acc[i][j], 0, 0, 0);
      __syncthreads();
    }
  }

#pragma unroll
  for (int j = 0; j < 4; j++) {
    int col = n0 + wn + (j << 4) + l16;        // output channel (may be >=256)
    float bcol = bias[col];
#pragma unroll
    for (int i = 0; i < 2; i++) {
#pragma unroll
      for (int r = 0; r < 4; r++) {
        int row = m0 + wm + (i << 4) + (quad << 2) + r;   // pixel
        float vv = acc[i][j][r] + bcol;
        if (relu) vv = fmaxf(vv, 0.f);
        if (Cb) Cb[((long long)bz * 4096 + row) * CO + col] = f2bf(vv);
        if (Cf) {
          long long oi = (((long long)bz * 256 + (col & 255)) << 12) + row;
          float ov = vv;
          if (addT) ov += addT[oi];
          float* dst = (col < 256) ? Cf : Cf2;
          dst[oi] = rnd ? bfround(ov) : ov;
        }
      }
    }
  }
}

// ---------------------------------------------------------------------------
// direct 3x3 SAME conv, fp32 in/out, weights (fp32) in LDS.
// grid (16, CO, B), block 256 (4 rows). Only used for the tiny CI=3 seg conv.
// ---------------------------------------------------------------------------
__global__ __launch_bounds__(256)
void conv3x3(const float* __restrict__ inF,
             const float* __restrict__ wgt, const float* __restrict__ bias,
             int CI, int CO, const float* __restrict__ addF,
             float* __restrict__ outF, int relu, int rnd)
{
  __shared__ float wsm[2304];
  int b = blockIdx.z, o = blockIdx.y, t = threadIdx.x;
  for (int i = t; i < CI * 9; i += 256) wsm[i] = wgt[(long long)o * CI * 9 + i];
  __syncthreads();
  int x = t & 63, y = (blockIdx.x << 2) + (t >> 6);
  bool ym = y > 0, yp = y < 63, xm = x > 0, xp = x < 63;
  int p = y * 64 + x;
  long long ibase = ((long long)b * CI) << 12;
  float acc = bias[o];
  for (int ci = 0; ci < CI; ci++) {
    const float* wp = &wsm[ci * 9];
    long long ib = ibase + ((long long)ci << 12) + p;
    float v00 = (ym && xm) ? inF[ib - 65] : 0.f;
    float v01 = ym ? inF[ib - 64] : 0.f;
    float v02 = (ym && xp) ? inF[ib - 63] : 0.f;
    float v10 = xm ? inF[ib - 1] : 0.f;
    float v11 = inF[ib];
    float v12 = xp ? inF[ib + 1] : 0.f;
    float v20 = (yp && xm) ? inF[ib + 63] : 0.f;
    float v21 = yp ? inF[ib + 64] : 0.f;
    float v22 = (yp && xp) ? inF[ib + 65] : 0.f;
    acc += v00 * wp[0] + v01 * wp[1] + v02 * wp[2]
         + v10 * wp[3] + v11 * wp[4] + v12 * wp[5]
         + v20 * wp[6] + v21 * wp[7] + v22 * wp[8];
  }
  if (relu) acc = fmaxf(acc, 0.f);
  long long oidx = (((long long)(b * CO + o)) << 12) + p;
  if (addF) acc += addF[oidx];
  outF[oidx] = rnd ? bfround(acc) : acc;
}

// ---------------------------------------------------------------------------
// Per-row softmax stats over fp32 cor (4096/row). grid 8192, block 256.
// statA[row] = {rmax1, 1/sum1, rmax2, 1/sum2};  confF[row] = conf.
// ---------------------------------------------------------------------------
__global__ __launch_bounds__(256)
void stats_rows(const float* __restrict__ corF,
                const unsigned char* __restrict__ mbits,
                float4* __restrict__ statA, float* __restrict__ confF)
{
  long long row = blockIdx.x;
  const float4* cr = (const float4*)(corF + (row << 12));
  const unsigned char* mr = mbits + row * 512;
  int t = threadIdx.x;

  float lg[16]; unsigned int mk[16];
#pragma unroll
  for (int i = 0; i < 4; i++) {
    float4 cc = cr[i * 256 + t];
    unsigned char mb = mr[(i * 256 + t) >> 1];
    int sh = (t & 1) << 2;
    lg[4 * i + 0] = cc.x; lg[4 * i + 1] = cc.y;
    lg[4 * i + 2] = cc.z; lg[4 * i + 3] = cc.w;
#pragma unroll
    for (int j = 0; j < 4; j++) mk[4 * i + j] = (mb >> (sh + j)) & 1u;
  }
  float m1 = -3.0e38f, m2 = -3.0e38f; int cnt = 0;
#pragma unroll
  for (int e = 0; e < 16; e++) {
    m1 = fmaxf(m1, lg[e]);
    if (!mk[e]) m2 = fmaxf(m2, lg[e]);
    cnt += (int)mk[e];
  }
  __shared__ float4 red4[256];
  red4[t] = make_float4(m1, m2, 0.f, 0.f); __syncthreads();
  for (int s = 128; s > 0; s >>= 1) {
    if (t < s) {
      red4[t].x = fmaxf(red4[t].x, red4[t + s].x);
      red4[t].y = fmaxf(red4[t].y, red4[t + s].y);
    }
    __syncthreads();
  }
  float rmax1 = red4[0].x;
  float rmax2 = fmaxf(red4[0].y, -10000.f);
  __syncthreads();

  float s1 = 0.f, cn = 0.f, s2 = 0.f;
#pragma unroll
  for (int e = 0; e < 16; e++) {
    float ex = __expf(fminf(lg[e] - rmax1, 0.f));
    s1 += ex;
    if (mk[e]) cn += ex;
    else s2 += __expf(fminf(lg[e] - rmax2, 0.f));
  }
  red4[t] = make_float4(s1, cn, s2, (float)cnt); __syncthreads();
  for (int s = 128; s > 0; s >>= 1) {
    if (t < s) {
      red4[t].x += red4[t + s].x; red4[t].y += red4[t + s].y;
      red4[t].z += red4[t + s].z; red4[t].w += red4[t + s].w;
    }
    __syncthreads();
  }
  if (t == 0) {
    float4 r = red4[0];
    float sum2 = r.z + r.w * __expf(fminf(-10000.f - rmax2, 0.f));
    statA[row] = make_float4(rmax1, 1.f / fmaxf(r.x, 1e-30f),
                             rmax2, 1.f / fmaxf(sum2, 1e-30f));
    confF[row] = r.y / fmaxf(r.x, 1e-30f);
  }
}

// ---------------------------------------------------------------------------
// Fused P·V GEMM, both modes in one dispatch (mode = blockIdx.y>>1).
// P reconstructed in-register from fp32 cor + bit mask + per-row stats.
// mode 0: P = mask ? exp(cor-rm1) : 0         (epilogue x 1/sum1) -> Cf0 (n,c)
// mode 1: P = mask ? exp(-1e4-rm2) : exp(cor-rm2)  (x 1/sum2)     -> Cf1 (c,n)
// Tile 32(rows) x 256(ALL cols), K-STEP 64 (vs pv4's 32): half the barrier
// pairs, 16 MFMA per step. Block 256 = 4 n-waves, wave tile 32x64.
// Grid (128, 2B) = 512 blocks. Reg-staged prefetch; cvt_pk bf16 pack.
// ---------------------------------------------------------------------------
__global__ __launch_bounds__(256, 2)
void gemm_pv4b(const float* __restrict__ corF,
               const unsigned char* __restrict__ mbits,
               const float4* __restrict__ statA,
               const unsigned short* __restrict__ Bt0,
               const unsigned short* __restrict__ Bt1,
               float* __restrict__ Cf0, float* __restrict__ Cf1)
{
  __shared__ unsigned short As[32][72];
  __shared__ unsigned short Bs[256][72];
  __shared__ float2 sstat[32];           // (-rm*log2e, iv) per A row
  int bz = blockIdx.y & 1, mode = blockIdx.y >> 1;
  const float* corb = corF + (long long)bz * 4096 * 4096;
  const unsigned char* mbb = mbits + (long long)bz * 4096 * 512;
  const unsigned short* Bb = (mode ? Bt1 : Bt0) + (long long)bz * 256 * 4096;
  int m0 = blockIdx.x << 5;
  int t = threadIdx.x;
  int lane = t & 63, wave = t >> 6, quad = lane >> 4, l16 = lane & 15;
  int wn = wave << 6;
  const float L2E = 1.44269504088896340736f;

  if (t < 32) {
    float4 s = statA[(long long)bz * 4096 + m0 + t];
    float rm = mode ? s.z : s.x, iv = mode ? s.w : s.y;
    sstat[t] = make_float2(-rm * L2E, iv);
  }
  __syncthreads();

  // A: row rA (32 rows), 8-elem k-chunk cA (full mask byte per thread);
  // B: rows (t>>2)+{0,64,128,192}, 2 chunks of 8 at (t&3)*8 and +32
  int rA = t >> 3, cA = (t & 7) << 3;
  int rB = t >> 2, cB = (t & 3) << 3;
  float nrmL = sstat[rA].x;                       // -rm*log2e
  float mvr = exp2f(-10000.f * L2E + nrmL);       // mode1 masked value (<=1)

  floatx4 acc[2][4] = {};

  const float* cpb = corb + (long long)(m0 + rA) * 4096 + cA;
  const unsigned char* mbp = mbb + (long long)(m0 + rA) * 512;
  const unsigned short* pbb = Bb + (long long)rB * 4096 + cB;

  float4 pa0, pa1; short8 pb[8]; unsigned int pmk;
  auto issue = [&](int kk) {
    pa0 = *(const float4*)(cpb + kk);
    pa1 = *(const float4*)(cpb + kk + 4);
    pmk = (unsigned int)mbp[(kk + cA) >> 3];      // 8 mask bits
#pragma unroll
    for (int j = 0; j < 4; j++)
#pragma unroll
      for (int h = 0; h < 2; h++)
        pb[j * 2 + h] = *(const short8*)(pbb + (long long)(j << 6) * 4096 + kk + (h << 5));
  };

  issue(0);
  for (int k0 = 0; k0 < 4096; k0 += 64) {
    // commit prefetched tile to LDS (A -> unnormalized P in bf16)
    {
      float cs[8] = {pa0.x, pa0.y, pa0.z, pa0.w, pa1.x, pa1.y, pa1.z, pa1.w};
      float vs[8];
#pragma unroll
      for (int j = 0; j < 8; j++) {
        float e = exp2f(fmaf(cs[j], L2E, nrmL));   // exp(c - rm)
        bool mk = (pmk >> j) & 1u;
        vs[j] = mode ? (mk ? mvr : e) : (mk ? e : 0.f);
      }
      union { unsigned int u4[4]; short8 s8; } pk;
      asm("v_cvt_pk_bf16_f32 %0, %1, %2" : "=v"(pk.u4[0]) : "v"(vs[0]), "v"(vs[1]));
      asm("v_cvt_pk_bf16_f32 %0, %1, %2" : "=v"(pk.u4[1]) : "v"(vs[2]), "v"(vs[3]));
      asm("v_cvt_pk_bf16_f32 %0, %1, %2" : "=v"(pk.u4[2]) : "v"(vs[4]), "v"(vs[5]));
      asm("v_cvt_pk_bf16_f32 %0, %1, %2" : "=v"(pk.u4[3]) : "v"(vs[6]), "v"(vs[7]));
      *(short8*)&As[rA][cA] = pk.s8;
#pragma unroll
      for (int j = 0; j < 4; j++)
#pragma unroll
        for (int h = 0; h < 2; h++)
          *(short8*)&Bs[rB + (j << 6)][cB + (h << 5)] = pb[j * 2 + h];
    }
    __syncthreads();
    if (k0 + 64 < 4096) issue(k0 + 64);   // hide HBM latency under MFMA phase
#pragma unroll
    for (int ks = 0; ks < 2; ks++) {
      short8 af[2], bfv[4];
#pragma unroll
      for (int i = 0; i < 2; i++)
        af[i] = *(const short8*)&As[(i << 4) + l16][(quad << 3) + (ks << 5)];
#pragma unroll
      for (int j = 0; j < 4; j++)
        bfv[j] = *(const short8*)&Bs[wn + (j << 4) + l16][(quad << 3) + (ks << 5)];
#pragma unroll
      for (int i = 0; i < 2; i++)
#pragma unroll
        for (int j = 0; j < 4; j++)
          acc[i][j] = __builtin_amdgcn_mfma_f32_16x16x32_bf16(af[i], bfv[j], acc[i][j], 0, 0, 0);
    }
    __syncthreads();
  }

#pragma unroll
  for (int j = 0; j < 4; j++) {
    int col = wn + (j << 4) + l16;        // c index < 256
#pragma unroll
    for (int i = 0; i < 2; i++) {
#pragma unroll
      for (int r = 0; r < 4; r++) {
        int lrow = (i << 4) + (quad << 2) + r;
        int row = m0 + lrow;
        float vv = bfround(acc[i][j][r] * sstat[lrow].y);   // x 1/sum
        if (mode) Cf1[(long long)bz * 256 * 4096 + (long long)col * 4096 + row] = vv;
        else      Cf0[(long long)bz * 4096 * 256 + (long long)row * 256 + col] = vv;
      }
    }
  }
}

// ---------------------------------------------------------------------------
// instance-norm stats of q (fp32) over spatial. grid (256, 2), block 256.
// ---------------------------------------------------------------------------
__global__ __launch_bounds__(256)
void inorm_stats(const float* __restrict__ q, float* __restrict__ mu, float* __restrict__ rs)
{
  int c = blockIdx.x, b = blockIdx.y, t = threadIdx.x;
  const float* base = q + ((long long)(b * 256 + c) << 12);
  float s = 0.f, s2 = 0.f;
  for (int i = t; i < 4096; i += 256) { float v = base[i]; s += v; s2 += v * v; }
  __shared__ float r1[256], r2[256];
  r1[t] = s; r2[t] = s2; __syncthreads();
  for (int st = 128; st > 0; st >>= 1) {
    if (t < st) { r1[t] += r1[t + st]; r2[t] += r2[t + st]; }
    __syncthreads();
  }
  if (t == 0) {
    float m = r1[0] * (1.f / 4096.f);
    float var = fmaxf(r2[0] * (1.f / 4096.f) - m * m, 0.f);
    mu[b * 256 + c] = m;
    rs[b * 256 + c] = rsqrtf(var + 1e-5f);
  }
}

// ---------------------------------------------------------------------------
// pono epilogue: t = out + (1-conf)*spade + q; y = channel-norm(t). fp32 (c,n).
// Also emits y transposed as bf16 (n,c) for the residual conv GEMMs.
// grid (4096, 2), block 256 (thread = channel)
// ---------------------------------------------------------------------------
__global__ __launch_bounds__(256)
void pono_y(const float* __restrict__ outF, const float* __restrict__ confF,
            const float* __restrict__ gF, const float* __restrict__ bF,
            const float* __restrict__ q, const float* __restrict__ mu,
            const float* __restrict__ rs, float* __restrict__ yF,
            unsigned short* __restrict__ yT)
{
  int n = blockIdx.x, b = blockIdx.y, c = threadIdx.x;
  long long cn = ((long long)(b * 256 + c) << 12) + n;
  float qv = q[cn];
  float sp = (qv - mu[b * 256 + c]) * rs[b * 256 + c] * (1.f + gF[cn]) + bF[cn];
  float cf = confF[b * 4096 + n];
  float tv = outF[((long long)(b * 4096 + n) << 8) + c] + (1.f - cf) * sp + qv;
  __shared__ float red[256];
  red[c] = tv; __syncthreads();
  for (int s = 128; s > 0; s >>= 1) { if (c < s) red[c] += red[c + s]; __syncthreads(); }
  float m = red[0] * (1.f / 256.f); __syncthreads();
  float d = tv - m;
  red[c] = d * d; __syncthreads();
  for (int s = 128; s > 0; s >>= 1) { if (c < s) red[c] += red[c + s]; __syncthreads(); }
  float var = fmaxf(red[0] * (1.f / 256.f), 0.f);
  float yv = d * rsqrtf(var + 1e-5f);
  yF[cn] = yv;
  yT[((long long)(b * 4096 + n) << 8) + c] = f2bf(yv);
}

// ---------------------------------------------------------------------------

extern "C" void kernel_launch(void* const* d_in, const int* in_sizes, int n_in,
                              void* d_out, int out_size, void* d_ws, size_t ws_size,
                              hipStream_t stream)
{
  (void)in_sizes; (void)n_in; (void)out_size; (void)ws_size;
  const int B = 2, CV = 256, CQK = 320, DP = 64, N = 4096, NH = 128, IC = 3;
  const int CQD = CQK + DP;   // 384 = fused projection width (exactly 3 tiles)
  const float INV_SQRT_CQK = 0.05590169943749474241f;  // 1/sqrt(320)

  const float* q    = (const float*)d_in[0];
  const float* k    = (const float*)d_in[1];
  const float* v    = (const float*)d_in[2];
  const float* pos  = (const float*)d_in[3];
  const float* seg  = (const float*)d_in[4];
  const float* v2   = (const float*)d_in[5];
  const float* f_w  = (const float*)d_in[6];
  const float* f_b  = (const float*)d_in[7];
  const float* g_w  = (const float*)d_in[8];
  const float* g_b  = (const float*)d_in[9];
  const float* h_w  = (const float*)d_in[10];
  const float* h_b  = (const float*)d_in[11];
  const float* fp_w = (const float*)d_in[12];
  const float* fp_b = (const float*)d_in[13];
  const float* gp_w = (const float*)d_in[14];
  const float* gp_b = (const float*)d_in[15];
  const float* sp_s_w = (const float*)d_in[16];
  const float* sp_s_b = (const float*)d_in[17];
  const float* sp_g_w = (const float*)d_in[18];
  const float* sp_g_b = (const float*)d_in[19];
  const float* sp_b_w = (const float*)d_in[20];
  const float* sp_b_b = (const float*)d_in[21];
  const float* r1_w = (const float*)d_in[22];
  const float* r1_b = (const float*)d_in[23];
  const float* r2_w = (const float*)d_in[24];
  const float* r2_b = (const float*)d_in[25];

  float* res_o  = (float*)d_out;
  float* out2_o = res_o + (long long)B * CV * N;
  float* cor_o  = res_o + 2ll * B * CV * N;

  // d_out overlays (dead until their real producer runs)
  unsigned short* query_t = (unsigned short*)cor_o;
  unsigned short* keyt_t  = query_t + (long long)B * N * CQK;
  float*          outBuf  = res_o;   // exactly B*N*CV floats

  // workspace carve (256B aligned), ~64 MB
  char* wp_ = (char*)d_ws;
  auto take = [&](size_t bytes) -> void* {
    void* r = wp_; wp_ += (bytes + 255) & ~(size_t)255; return r;
  };
  unsigned short* v_t     = (unsigned short*)take((size_t)B * N * CV * 2);
  unsigned short* qfq_t   = (unsigned short*)take((size_t)B * N * CQD * 2);  // qf|qp fused
  unsigned short* kfq_t   = (unsigned short*)take((size_t)B * N * CQD * 2);  // kf|kp fused
  unsigned short* vh      = (unsigned short*)take((size_t)B * CV * N * 2);
  unsigned short* v2b     = (unsigned short*)take((size_t)B * CV * N * 2);
  unsigned short* fqwB    = (unsigned short*)take((size_t)CQD * CQK * 2);    // f_w|fp_w
  unsigned short* gqwB    = (unsigned short*)take((size_t)CQD * CQK * 2);    // g_w|gp_w
  unsigned short* hwB     = (unsigned short*)take((size_t)CV * CV * 2);
  unsigned short* maskB16 = (unsigned short*)take((size_t)B * N * 256 * 2);
  float4*         statA   = (float4*)take((size_t)B * N * 16);
  float*          confF   = (float*)take((size_t)B * N * 4);
  float*          muF     = (float*)take((size_t)B * CV * 4);
  float*          rsF     = (float*)take((size_t)B * CV * 4);
  float*          rnormQ  = (float*)take((size_t)B * N * 4);
  float*          rnormK  = (float*)take((size_t)B * N * 4);
  float*          actv    = (float*)take((size_t)B * NH * N * 4);
  float*          gC      = (float*)take((size_t)B * CV * N * 4);
  float*          bC      = (float*)take((size_t)B * CV * N * 4);
  float*          yF      = (float*)take((size_t)B * CV * N * 4);
  // prepacked conv weights, bf16 [o][tap][ci]; SPADE gamma+beta concatenated
  unsigned short* spW9    = (unsigned short*)take((size_t)2 * CV * 9 * NH * 2);
  unsigned short* r1W9    = (unsigned short*)take((size_t)CV * 9 * CV * 2);
  unsigned short* r2W9    = (unsigned short*)take((size_t)CV * 9 * CV * 2);
  float*          spBias  = (float*)take((size_t)2 * CV * 4);
  float*          fqBias  = (float*)take((size_t)CQD * 4);
  float*          gqBias  = (float*)take((size_t)CQD * 4);
  // bf16 pixel-major conv activations — reuse regions dead by SPADE time:
  unsigned short* yT      = qfq_t;  // B*N*256*2 = 4 MB  <= 6.3 MB (dead after cor/mask GEMMs)
  unsigned short* a1T     = kfq_t;  // 4 MB <= 6.3 MB
  unsigned short* actvT   = v_t;    // B*N*128*2 = 2 MB  <= 4 MB    (dead after vh GEMM)

  dim3 blk(256);
  auto cvt = [&](const float* in, unsigned short* out, int n) {
    cvt_f2b<<<dim3((n + 255) / 256), blk, 0, stream>>>(in, out, n);
  };
  auto prepw = [&](const float* w, unsigned short* w9, int CO, int CI) {
    prep_w9<<<dim3((CO * CI * 9 + 255) / 256), blk, 0, stream>>>(w, w9, CO, CI);
  };
  auto gemm = [&](const unsigned short* A, long long sAb, int lda,
                  const unsigned short* Bt, long long sBb, int ldb,
                  int M, int Nc, int K, float alpha,
                  const float* bias, int biasMode,
                  unsigned short* Cb, long long sCbb, int ldcb,
                  float* Cf, long long sCfb, int ldcf,
                  unsigned short* Cm) {
    dim3 grid((Nc + 127) / 128, M / 128, B);
    gemm_bt<<<grid, blk, 0, stream>>>(A, sAb, lda, Bt, sBb, ldb, Nc, K, alpha,
                                      bias, biasMode, Cb, sCbb, ldcb,
                                      Cf, sCfb, ldcf, Cm);
  };
  auto conv = [&](const unsigned short* Xt, int CI, const unsigned short* W9,
                  int CO, const float* bias, unsigned short* Cb, int relu,
                  float* Cf, const float* addT, int rnd, float* Cf2) {
    gemm_conv2<<<dim3(CO / 128, N / 64, B), blk, 0, stream>>>(
        Xt, CI, W9, CO, bias, Cb, relu, Cf, addT, rnd, Cf2);
  };

  // 0) fp32 -> bf16 conversions (weights, v2) + conv weight prepacks.
  //    Projection weights/biases concatenated: [f|fp] and [g|gp].
  cvt(f_w, fqwB, CQK * CQK);
  cvt(fp_w, fqwB + (size_t)CQK * CQK, DP * CQK);
  cvt(g_w, gqwB, CQK * CQK);
  cvt(gp_w, gqwB + (size_t)CQK * CQK, DP * CQK);
  cvt(h_w, hwB, CV * CV);
  cvt(v2, v2b, B * CV * N);
  prepw(sp_g_w, spW9, CV, NH);
  prepw(sp_b_w, spW9 + (size_t)CV * 9 * NH, CV, NH);
  prepw(r1_w, r1W9, CV, CV);
  prepw(r2_w, r2W9, CV, CV);
  hipMemcpyAsync(spBias, sp_g_b, CV * sizeof(float), hipMemcpyDeviceToDevice, stream);
  hipMemcpyAsync(spBias + CV, sp_b_b, CV * sizeof(float), hipMemcpyDeviceToDevice, stream);
  hipMemcpyAsync(fqBias, f_b, CQK * sizeof(float), hipMemcpyDeviceToDevice, stream);
  hipMemcpyAsync(fqBias + CQK, fp_b, DP * sizeof(float), hipMemcpyDeviceToDevice, stream);
  hipMemcpyAsync(gqBias, g_b, CQK * sizeof(float), hipMemcpyDeviceToDevice, stream);
  hipMemcpyAsync(gqBias + CQK, gp_b, DP * sizeof(float), hipMemcpyDeviceToDevice, stream);

  // 1) normalized-q/k + pos concat, (n,c) bf16 (into cor-region overlay),
  //    coalesced: colnorm (column 1/(||.||+eps)) then LDS-transpose build
  colnorm<<<dim3(128, B), blk, 0, stream>>>(q, rnormQ);
  colnorm<<<dim3(128, B), blk, 0, stream>>>(k, rnormK);
  build_qk3<<<dim3(64, 5, B), blk, 0, stream>>>(q, pos, rnormQ, query_t);
  build_qk3<<<dim3(64, 5, B), blk, 0, stream>>>(k, pos, rnormK, keyt_t);
  // 2) v -> (n,c) bf16
  transpose_c<<<dim3(64, 4, B), blk, 0, stream>>>(v, v_t, CV);

  // 3) fused conv1x1 projections: [qf|qp] = query @ [f_w|fp_w]^T (N=384,
  //    exactly 3 col-tiles, zero pad waste); same for [kf|kp].
  gemm(query_t, (long long)N * CQK, CQK, fqwB, 0, CQK, N, CQD, CQK, 1.f, fqBias, 1,
       qfq_t, (long long)N * CQD, CQD, nullptr, 0, 0, nullptr);
  gemm(keyt_t, (long long)N * CQK, CQK, gqwB, 0, CQK, N, CQD, CQK, 1.f, gqBias, 1,
       kfq_t, (long long)N * CQD, CQD, nullptr, 0, 0, nullptr);
  // vh = h_w @ v : (c,n) bf16, bias per row
  gemm(hwB, 0, CV, v_t, (long long)N * CV, CV, CV, N, CV, 1.f, h_b, 2,
       vh, (long long)CV * N, N, nullptr, 0, 0, nullptr);

  // 4) cor = Q K^T / sqrt(320) -> fp32 into d_out (overlay now dead).
  //    A/B are the first 320 cols of the fused buffers (lda/ldb = 384).
  gemm(qfq_t, (long long)N * CQD, CQD, kfq_t, (long long)N * CQD, CQD, N, N, CQK,
       INV_SQRT_CQK, nullptr, 0, nullptr, 0, 0,
       cor_o, (long long)N * N, N, nullptr);
  // 5) mask bits = (Qp Kp^T > 0); A/B at col offset 320 of fused buffers
  gemm(qfq_t + CQK, (long long)N * CQD, CQD, kfq_t + CQK, (long long)N * CQD, CQD,
       N, N, DP, 1.f,
       nullptr, 0, nullptr, 0, 0, nullptr, 0, 0, maskB16);

  // 6) per-row softmax stats + conf
  stats_rows<<<dim3(B * N), blk, 0, stream>>>(cor_o, (const unsigned char*)maskB16,
                                              statA, confF);
  // 7+8) fused: out = (softmax(cor)*mask) @ V -> (n,c) fp32 (res overlay);
  //      out2 = softmax(mask ? -1e4 : cor) @ V2 -> (c,n) fp32 output
  gemm_pv4b<<<dim3(128, 2 * B), blk, 0, stream>>>(
      cor_o, (const unsigned char*)maskB16, statA, vh, v2b, outBuf, out2_o);

  // 9) SPADE branch: tiny seg conv direct fp32; gamma+beta as ONE merged
  //    512-channel MFMA conv (A staged once, 512 blocks)
  inorm_stats<<<dim3(CV, B), blk, 0, stream>>>(q, muF, rsF);
  conv3x3<<<dim3(16, NH, B), blk, 0, stream>>>(seg, sp_s_w, sp_s_b, IC, NH, nullptr, actv, 1, 0);
  transpose_c<<<dim3(64, 2, B), blk, 0, stream>>>(actv, actvT, NH);
  conv(actvT, NH, spW9, 2 * CV, spBias, nullptr, 0, gC, nullptr, 0, bC);
  // 10) pono (emits yF fp32 (c,n) + yT bf16 (n,c))
  pono_y<<<dim3(N, B), blk, 0, stream>>>(outBuf, confF, gC, bC, q, muF, rsF, yF, yT);
  // 11) residual convs as MFMA GEMMs:
  //     a1T = relu(conv(yT)) bf16 (n,c);  res = conv(a1T) + yF, bf16-rounded
  conv(yT, CV, r1W9, CV, r1_b, a1T, 1, nullptr, nullptr, 0, nullptr);
  conv(a1T, CV, r2W9, CV, r2_b, nullptr, 0, res_o, yF, 1, nullptr);
}